// Round 1
// baseline (364.152 us; speedup 1.0000x reference)
//
#include <hip/hip_runtime.h>
#include <hip/hip_bf16.h>

// MHA forward: B=2, S=2048, E=1024, H=16, D=64, causal mask.
// Pipeline: wt_kernel (W -> W^T bf16) ; gemm_k<f32A,heads> (QKV proj) ;
//           attn_k (flash attention) ; gemm_k<bf16A,f32out> (output proj).

#define BB 2
#define SS 2048
#define EE 1024
#define HH 16
#define DD 64

typedef __bf16 bf16;
typedef __attribute__((ext_vector_type(8))) __bf16 bf16x8;
typedef __attribute__((ext_vector_type(4))) float f32x4;

// ---------------- weights: Wt[n][k] = bf16(W[k][n]) ----------------
__global__ __launch_bounds__(256) void wt_kernel(
    const float* __restrict__ w0, const float* __restrict__ w1,
    const float* __restrict__ w2, const float* __restrict__ w3,
    bf16* __restrict__ out) {
  __shared__ float tile[32][33];
  const float* W = blockIdx.z == 0 ? w0 : blockIdx.z == 1 ? w1 : blockIdx.z == 2 ? w2 : w3;
  bf16* o = out + (size_t)blockIdx.z * EE * EE;
  const int k0 = blockIdx.y * 32, n0 = blockIdx.x * 32;
  const int tx = threadIdx.x, ty = threadIdx.y;
#pragma unroll
  for (int j = 0; j < 4; ++j)
    tile[ty + j * 8][tx] = W[(size_t)(k0 + ty + j * 8) * EE + n0 + tx];
  __syncthreads();
#pragma unroll
  for (int j = 0; j < 4; ++j)
    o[(size_t)(n0 + ty + j * 8) * EE + k0 + tx] = (bf16)tile[tx][ty + j * 8];
}

// ---------------- GEMM: C[M=4096][N=1024] = A[M][1024] @ Wt^T + bias ----------------
// Wt is [N][K] bf16. A_F32: A is f32 (converted during staging), else bf16.
// OUT_HEADS: write bf16 to [B,H,S,D] (z selects Q/K/V); else f32 row-major.
template <bool A_F32, bool OUT_HEADS>
__global__ __launch_bounds__(256) void gemm_k(
    const void* __restrict__ a0, const void* __restrict__ a1, const void* __restrict__ a2,
    const bf16* __restrict__ wtb, const float* __restrict__ bias0,
    const float* __restrict__ bias1, const float* __restrict__ bias2,
    void* __restrict__ outb) {
  constexpr int Kd = EE, Nd = EE;
  __shared__ __align__(16) bf16 Asm[128][40];  // pad 32->40: 16B-aligned rows, 2-way max
  __shared__ __align__(16) bf16 Bsm[128][40];
  const int z = blockIdx.z;
  const void* a = z == 0 ? a0 : z == 1 ? a1 : a2;
  const bf16* wt = wtb + (size_t)z * EE * EE;
  const float* bias = z == 0 ? bias0 : z == 1 ? bias1 : bias2;
  const int m0 = blockIdx.y * 128, n0 = blockIdx.x * 128;
  const int t = threadIdx.x, lane = t & 63, wid = t >> 6;
  const int wm = wid >> 1, wn = wid & 1, lg = lane >> 4, lr = lane & 15;
  const int sm = t >> 1, sc = (t & 1) * 16;

  f32x4 acc[4][4];
#pragma unroll
  for (int i = 0; i < 4; ++i)
#pragma unroll
    for (int j = 0; j < 4; ++j) acc[i][j] = (f32x4)0.0f;

  for (int kk = 0; kk < Kd; kk += 32) {
    if constexpr (A_F32) {
      const float* src = (const float*)a + (size_t)(m0 + sm) * Kd + kk + sc;
      f32x4 f0 = *(const f32x4*)(src);
      f32x4 f1 = *(const f32x4*)(src + 4);
      f32x4 f2 = *(const f32x4*)(src + 8);
      f32x4 f3 = *(const f32x4*)(src + 12);
      bf16x8 w0, w1;
#pragma unroll
      for (int i = 0; i < 4; ++i) {
        w0[i] = (bf16)f0[i];
        w0[i + 4] = (bf16)f1[i];
        w1[i] = (bf16)f2[i];
        w1[i + 4] = (bf16)f3[i];
      }
      *(bf16x8*)&Asm[sm][sc] = w0;
      *(bf16x8*)&Asm[sm][sc + 8] = w1;
    } else {
      const bf16* src = (const bf16*)a + (size_t)(m0 + sm) * Kd + kk + sc;
      *(bf16x8*)&Asm[sm][sc] = *(const bf16x8*)src;
      *(bf16x8*)&Asm[sm][sc + 8] = *(const bf16x8*)(src + 8);
    }
    {
      const bf16* src = wt + (size_t)(n0 + sm) * Kd + kk + sc;
      *(bf16x8*)&Bsm[sm][sc] = *(const bf16x8*)src;
      *(bf16x8*)&Bsm[sm][sc + 8] = *(const bf16x8*)(src + 8);
    }
    __syncthreads();
    bf16x8 af[4], bf[4];
#pragma unroll
    for (int i = 0; i < 4; ++i) af[i] = *(const bf16x8*)&Asm[wm * 64 + i * 16 + lr][lg * 8];
#pragma unroll
    for (int j = 0; j < 4; ++j) bf[j] = *(const bf16x8*)&Bsm[wn * 64 + j * 16 + lr][lg * 8];
#pragma unroll
    for (int i = 0; i < 4; ++i)
#pragma unroll
      for (int j = 0; j < 4; ++j)
        acc[i][j] = __builtin_amdgcn_mfma_f32_16x16x32_bf16(af[i], bf[j], acc[i][j], 0, 0, 0);
    __syncthreads();
  }
#pragma unroll
  for (int i = 0; i < 4; ++i)
#pragma unroll
    for (int j = 0; j < 4; ++j) {
      const int col = n0 + wn * 64 + j * 16 + lr;
      const float bv = bias[col];
      const int row0 = m0 + wm * 64 + i * 16 + lg * 4;
#pragma unroll
      for (int r = 0; r < 4; ++r) {
        const int row = row0 + r;
        const float val = acc[i][j][r] + bv;
        if constexpr (OUT_HEADS) {
          bf16* o = (bf16*)outb + (size_t)z * BB * SS * EE;
          const int hh = col >> 6, dd = col & 63, bb = row >> 11, ss = row & 2047;
          o[(((size_t)bb * HH + hh) * SS + ss) * DD + dd] = (bf16)val;
        } else {
          ((float*)outb)[(size_t)row * Nd + col] = val;
        }
      }
    }
}

// ---------------- flash attention, causal ----------------
// grid (S/64, H, B), 256 threads = 4 waves; wave w owns q rows [qt*64+w*16, +16)
__global__ __launch_bounds__(256) void attn_k(const bf16* __restrict__ qkvh,
                                              bf16* __restrict__ ao) {
  __shared__ __align__(16) bf16 Ksm[64][72];   // [kv][d], pad 64->72
  __shared__ __align__(16) bf16 Vtsm[64][72];  // [d][kv], transposed
  __shared__ __align__(16) bf16 Psm[4][16][72];  // per-wave P tile
  const int qt = blockIdx.x, h = blockIdx.y, b = blockIdx.z;
  const size_t hb = ((size_t)b * HH + h) * SS * DD;
  const bf16* Q = qkvh + hb;
  const bf16* Kp = qkvh + (size_t)BB * HH * SS * DD + hb;
  const bf16* Vp = qkvh + 2 * (size_t)BB * HH * SS * DD + hb;
  const int t = threadIdx.x, lane = t & 63, wid = t >> 6;
  const int lg = lane >> 4, lr = lane & 15;
  const int q0 = qt * 64;
  const int qrow = q0 + wid * 16 + lr;

  bf16x8 qf[2];
  qf[0] = *(const bf16x8*)&Q[(size_t)qrow * DD + lg * 8];
  qf[1] = *(const bf16x8*)&Q[(size_t)qrow * DD + 32 + lg * 8];

  f32x4 o[4];
#pragma unroll
  for (int dt = 0; dt < 4; ++dt) o[dt] = (f32x4)0.0f;
  float mrun[4], lrun[4];
#pragma unroll
  for (int r = 0; r < 4; ++r) {
    mrun[r] = -INFINITY;
    lrun[r] = 0.0f;
  }

  const int sr = t >> 2, scol = (t & 3) * 16;

  for (int kt = 0; kt <= qt; ++kt) {
    const int kv0 = kt * 64;
    {  // stage K [kv][d]
      const bf16* ks = &Kp[(size_t)(kv0 + sr) * DD + scol];
      *(bf16x8*)&Ksm[sr][scol] = *(const bf16x8*)ks;
      *(bf16x8*)&Ksm[sr][scol + 8] = *(const bf16x8*)(ks + 8);
    }
    {  // stage V transposed -> Vtsm[d][kv]
      const bf16* vs = &Vp[(size_t)(kv0 + sr) * DD + scol];
      bf16x8 v0 = *(const bf16x8*)vs, v1 = *(const bf16x8*)(vs + 8);
#pragma unroll
      for (int i = 0; i < 8; ++i) {
        Vtsm[scol + i][sr] = v0[i];
        Vtsm[scol + 8 + i][sr] = v1[i];
      }
    }
    __syncthreads();

    // S = Q K^T / 8 : 16x64 per wave
    f32x4 s[4];
#pragma unroll
    for (int n = 0; n < 4; ++n) {
      f32x4 c = (f32x4)0.0f;
#pragma unroll
      for (int kc = 0; kc < 2; ++kc) {
        bf16x8 kf = *(const bf16x8*)&Ksm[n * 16 + lr][kc * 32 + lg * 8];
        c = __builtin_amdgcn_mfma_f32_16x16x32_bf16(qf[kc], kf, c, 0, 0, 0);
      }
      s[n] = c * 0.125f;
    }
    if (kt == qt) {  // causal mask on diagonal tile
#pragma unroll
      for (int n = 0; n < 4; ++n) {
        const int kv = kv0 + n * 16 + lr;
#pragma unroll
        for (int r = 0; r < 4; ++r) {
          const int qq = q0 + wid * 16 + lg * 4 + r;
          if (kv > qq) s[n][r] = -1e30f;
        }
      }
    }
    // online softmax: rows live in 16-lane groups
    float alpha[4];
#pragma unroll
    for (int r = 0; r < 4; ++r) {
      float tm = fmaxf(fmaxf(s[0][r], s[1][r]), fmaxf(s[2][r], s[3][r]));
      tm = fmaxf(tm, __shfl_xor(tm, 1));
      tm = fmaxf(tm, __shfl_xor(tm, 2));
      tm = fmaxf(tm, __shfl_xor(tm, 4));
      tm = fmaxf(tm, __shfl_xor(tm, 8));
      const float mnew = fmaxf(mrun[r], tm);
      alpha[r] = __expf(mrun[r] - mnew);
      mrun[r] = mnew;
    }
    float rsum[4];
#pragma unroll
    for (int r = 0; r < 4; ++r) {
      float acc = 0.0f;
#pragma unroll
      for (int n = 0; n < 4; ++n) {
        const float p = __expf(s[n][r] - mrun[r]);
        s[n][r] = p;
        acc += p;
      }
      acc += __shfl_xor(acc, 1);
      acc += __shfl_xor(acc, 2);
      acc += __shfl_xor(acc, 4);
      acc += __shfl_xor(acc, 8);
      lrun[r] = lrun[r] * alpha[r] + acc;
      rsum[r] = acc;
    }
#pragma unroll
    for (int dt = 0; dt < 4; ++dt)
#pragma unroll
      for (int r = 0; r < 4; ++r) o[dt][r] *= alpha[r];
    // P (C-layout) -> LDS -> A-fragments (per-wave buffer, in-order LDS ok)
#pragma unroll
    for (int n = 0; n < 4; ++n)
#pragma unroll
      for (int r = 0; r < 4; ++r) Psm[wid][lg * 4 + r][n * 16 + lr] = (bf16)s[n][r];
    bf16x8 pf[2];
    pf[0] = *(const bf16x8*)&Psm[wid][lr][lg * 8];
    pf[1] = *(const bf16x8*)&Psm[wid][lr][32 + lg * 8];
#pragma unroll
    for (int dt = 0; dt < 4; ++dt)
#pragma unroll
      for (int kc = 0; kc < 2; ++kc) {
        bf16x8 vf = *(const bf16x8*)&Vtsm[dt * 16 + lr][kc * 32 + lg * 8];
        o[dt] = __builtin_amdgcn_mfma_f32_16x16x32_bf16(pf[kc], vf, o[dt], 0, 0, 0);
      }
    __syncthreads();
  }
#pragma unroll
  for (int dt = 0; dt < 4; ++dt) {
    const int d = dt * 16 + lr;
#pragma unroll
    for (int r = 0; r < 4; ++r) {
      const int qq = q0 + wid * 16 + lg * 4 + r;
      ao[((size_t)b * SS + qq) * EE + h * DD + d] = (bf16)(o[dt][r] / lrun[r]);
    }
  }
}

extern "C" void kernel_launch(void* const* d_in, const int* in_sizes, int n_in,
                              void* d_out, int out_size, void* d_ws, size_t ws_size,
                              hipStream_t stream) {
  const float* v = (const float*)d_in[0];
  const float* k = (const float*)d_in[1];
  const float* q = (const float*)d_in[2];
  // d_in[3] = mask: strictly-causal by construction; applied analytically.
  const float* wq = (const float*)d_in[4];
  const float* bq = (const float*)d_in[5];
  const float* wk = (const float*)d_in[6];
  const float* bk = (const float*)d_in[7];
  const float* wv = (const float*)d_in[8];
  const float* bv = (const float*)d_in[9];
  const float* wo = (const float*)d_in[10];
  const float* bo = (const float*)d_in[11];

  bf16* wt = (bf16*)d_ws;                      // [4][E][E]   (wq,wk,wv,wo transposed)
  bf16* qkvh = wt + (size_t)4 * EE * EE;       // [3][B][H][S][D]
  bf16* ao = qkvh + (size_t)3 * BB * SS * EE;  // [B][S][E]
  // total ws use: 20M bf16 = 40 MB

  wt_kernel<<<dim3(EE / 32, EE / 32, 4), dim3(32, 8), 0, stream>>>(wq, wk, wv, wo, wt);
  gemm_k<true, true><<<dim3(EE / 128, (BB * SS) / 128, 3), 256, 0, stream>>>(
      q, k, v, wt, bq, bk, bv, qkvh);
  attn_k<<<dim3(SS / 64, HH, BB), 256, 0, stream>>>(qkvh, ao);
  gemm_k<false, false><<<dim3(EE / 128, (BB * SS) / 128, 1), 256, 0, stream>>>(
      ao, ao, ao, wt + (size_t)3 * EE * EE, bo, bo, bo, d_out);
}

// Round 3
// 296.065 us; speedup vs baseline: 1.2300x; 1.2300x over previous
//
#include <hip/hip_runtime.h>
#include <hip/hip_bf16.h>

// MHA forward: B=2, S=2048, E=1024, H=16, D=64, causal.
// cvt_k (q,k,v f32->bf16) ; wt_kernel (W->W^T bf16) ;
// gemm2<128,true> QKV proj (global_load_lds + XOR swizzle) ;
// attn_k (flash, 8 waves, qtile=128) ; gemm2<64,false> out proj.

#define BB 2
#define SS 2048
#define EE 1024
#define HH 16
#define DD 64

typedef __bf16 bf16;
typedef __attribute__((ext_vector_type(8))) __bf16 bf16x8;
typedef __attribute__((ext_vector_type(8))) unsigned short u16x8;
typedef __attribute__((ext_vector_type(4))) float f32x4;

__device__ __forceinline__ void gload16(const void* g, void* l) {
  __builtin_amdgcn_global_load_lds(
      (const __attribute__((address_space(1))) unsigned*)g,
      (__attribute__((address_space(3))) unsigned*)l, 16, 0, 0);
}

// ---------------- f32 -> bf16 convert (q,k,v) ----------------
__global__ __launch_bounds__(256) void cvt_k(
    const float* __restrict__ q, const float* __restrict__ k, const float* __restrict__ v,
    bf16* __restrict__ qb, bf16* __restrict__ kb, bf16* __restrict__ vb) {
  const int z = blockIdx.y;
  const float* s = z == 0 ? q : z == 1 ? k : v;
  bf16* d = z == 0 ? qb : z == 1 ? kb : vb;
  const size_t N8 = (size_t)BB * SS * EE / 8;
  for (size_t i = (size_t)blockIdx.x * 256 + threadIdx.x; i < N8; i += (size_t)gridDim.x * 256) {
    f32x4 a = *(const f32x4*)(s + i * 8);
    f32x4 b = *(const f32x4*)(s + i * 8 + 4);
    bf16x8 o;
#pragma unroll
    for (int j = 0; j < 4; ++j) {
      o[j] = (bf16)a[j];
      o[j + 4] = (bf16)b[j];
    }
    *(bf16x8*)(d + i * 8) = o;
  }
}

// ---------------- weights: Wt[n][k] = bf16(W[k][n]) ----------------
__global__ __launch_bounds__(256) void wt_kernel(
    const float* __restrict__ w0, const float* __restrict__ w1,
    const float* __restrict__ w2, const float* __restrict__ w3,
    bf16* __restrict__ out) {
  __shared__ float tile[32][33];
  const float* W = blockIdx.z == 0 ? w0 : blockIdx.z == 1 ? w1 : blockIdx.z == 2 ? w2 : w3;
  bf16* o = out + (size_t)blockIdx.z * EE * EE;
  const int k0 = blockIdx.y * 32, n0 = blockIdx.x * 32;
  const int tx = threadIdx.x, ty = threadIdx.y;
#pragma unroll
  for (int j = 0; j < 4; ++j)
    tile[ty + j * 8][tx] = W[(size_t)(k0 + ty + j * 8) * EE + n0 + tx];
  __syncthreads();
#pragma unroll
  for (int j = 0; j < 4; ++j)
    o[(size_t)(n0 + ty + j * 8) * EE + k0 + tx] = (bf16)tile[tx][ty + j * 8];
}

// ---------------- GEMM: C[M][N] = A[M][K] @ Wt[N][K]^T + bias ----------------
// BK=64, 128xBN tile, 4 waves (2x2). global_load_lds staging, XOR swizzle:
// linear LDS dest, pre-swizzled global source granule, XOR'd ds_read_b128.
template <int BN, bool OUT_HEADS>
__global__ __launch_bounds__(256) void gemm2(
    const bf16* __restrict__ a0, const bf16* __restrict__ a1, const bf16* __restrict__ a2,
    const bf16* __restrict__ wtb, const float* __restrict__ bias0,
    const float* __restrict__ bias1, const float* __restrict__ bias2,
    void* __restrict__ outb) {
  constexpr int Kd = EE;
  constexpr int NJ = BN / 32;  // B-frags per wave == B staging chunks
  __shared__ __align__(16) bf16 Asm[128 * 64];
  __shared__ __align__(16) bf16 Bsm[BN * 64];
  const int t = threadIdx.x, lane = t & 63, w = t >> 6;
  const int lr = lane & 15, lg = lane >> 4;
  const int wm = w >> 1, wn = w & 1;
  const int m0 = blockIdx.y * 128, n0 = blockIdx.x * BN;
  const int z = blockIdx.z;
  const bf16* a = z == 0 ? a0 : z == 1 ? a1 : a2;
  const bf16* wt = wtb + (size_t)z * EE * EE;
  const float* bias = z == 0 ? bias0 : z == 1 ? bias1 : bias2;

  const int srow = lane >> 3;                // row within 8-row chunk
  const int acol = ((lane & 7) ^ srow) * 8;  // pre-swizzled source granule

  f32x4 acc[4][NJ];
#pragma unroll
  for (int i = 0; i < 4; ++i)
#pragma unroll
    for (int j = 0; j < NJ; ++j) acc[i][j] = (f32x4)0.0f;

  for (int kk = 0; kk < Kd; kk += 64) {
#pragma unroll
    for (int j = 0; j < 4; ++j) {  // A: 128 rows = 4 chunks of 32
      const int row = j * 32 + w * 8 + srow;
      gload16(a + (size_t)(m0 + row) * Kd + kk + acol, (char*)Asm + j * 4096 + w * 1024);
    }
#pragma unroll
    for (int j = 0; j < NJ; ++j) {  // B: BN rows = BN/32 chunks of 32
      const int row = j * 32 + w * 8 + srow;
      gload16(wt + (size_t)(n0 + row) * Kd + kk + acol, (char*)Bsm + j * 4096 + w * 1024);
    }
    __syncthreads();
#pragma unroll
    for (int kc = 0; kc < 2; ++kc) {
      bf16x8 A4[4], B4[NJ];
#pragma unroll
      for (int i = 0; i < 4; ++i) {
        const int r = wm * 64 + i * 16 + lr;
        A4[i] = *(const bf16x8*)((const char*)Asm + r * 128 + ((kc * 64 + lg * 16) ^ ((r & 7) << 4)));
      }
#pragma unroll
      for (int j = 0; j < NJ; ++j) {
        const int r = wn * (BN / 2) + j * 16 + lr;
        B4[j] = *(const bf16x8*)((const char*)Bsm + r * 128 + ((kc * 64 + lg * 16) ^ ((r & 7) << 4)));
      }
#pragma unroll
      for (int i = 0; i < 4; ++i)
#pragma unroll
        for (int j = 0; j < NJ; ++j)
          acc[i][j] = __builtin_amdgcn_mfma_f32_16x16x32_bf16(A4[i], B4[j], acc[i][j], 0, 0, 0);
    }
    __syncthreads();
  }
#pragma unroll
  for (int i = 0; i < 4; ++i)
#pragma unroll
    for (int j = 0; j < NJ; ++j) {
      const int col = n0 + wn * (BN / 2) + j * 16 + lr;
      const float bv = bias[col];
      const int row0 = m0 + wm * 64 + i * 16 + lg * 4;
#pragma unroll
      for (int r = 0; r < 4; ++r) {
        const int row = row0 + r;
        const float val = acc[i][j][r] + bv;
        if constexpr (OUT_HEADS) {
          bf16* o = (bf16*)outb + (size_t)z * BB * SS * EE;
          const int hh = col >> 6, dd = col & 63, bb = row >> 11, ss = row & 2047;
          o[(((size_t)bb * HH + hh) * SS + ss) * DD + dd] = (bf16)val;
        } else {
          ((float*)outb)[(size_t)row * EE + col] = val;
        }
      }
    }
}

// ---------------- flash attention, causal ----------------
// grid (S/128, H, B) with reversed qtile order; 512 threads = 8 waves,
// wave w owns q rows [J*128 + w*16, +16).
__global__ __launch_bounds__(512) void attn_k(const bf16* __restrict__ qkvh,
                                              bf16* __restrict__ ao) {
  __shared__ __align__(16) bf16 Ksm[64 * 64];    // linear, swizzled (gload_lds)
  __shared__ __align__(16) bf16 Vtsm[64][72];    // [d][kv], XOR-swizzled kv bytes
  __shared__ __align__(16) bf16 Psm[8][16][72];  // per-wave P tile
  const int J = (int)gridDim.x - 1 - (int)blockIdx.x;  // long blocks first
  const int h = blockIdx.y, b = blockIdx.z;
  const size_t hb = ((size_t)b * HH + h) * SS * DD;
  const bf16* Q = qkvh + hb;
  const bf16* Kp = qkvh + (size_t)BB * HH * SS * DD + hb;
  const bf16* Vp = qkvh + 2 * (size_t)BB * HH * SS * DD + hb;
  const int t = threadIdx.x, lane = t & 63, w = t >> 6;
  const int lg = lane >> 4, lr = lane & 15;
  const int q0 = J * 128;
  const int qrow = q0 + w * 16 + lr;

  bf16x8 qf[2];
  qf[0] = *(const bf16x8*)&Q[(size_t)qrow * DD + lg * 8];
  qf[1] = *(const bf16x8*)&Q[(size_t)qrow * DD + 32 + lg * 8];

  f32x4 o[4];
#pragma unroll
  for (int dt = 0; dt < 4; ++dt) o[dt] = (f32x4)0.0f;
  float mrun[4], lrun[4];
#pragma unroll
  for (int r = 0; r < 4; ++r) {
    mrun[r] = -INFINITY;
    lrun[r] = 0.0f;
  }

  const int srow = lane >> 3;
  const int kcol = ((lane & 7) ^ srow) * 8;  // pre-swizzled K source granule
  const int lastkt = 2 * J + (w >> 2);

  for (int kt = 0; kt <= 2 * J + 1; ++kt) {
    const int kv0 = kt * 64;
    if (w < 4) {  // stage K via global_load_lds (2 chunks of 8 rows per wave)
#pragma unroll
      for (int j = 0; j < 2; ++j) {
        const int row = j * 32 + w * 8 + srow;
        gload16(Kp + (size_t)(kv0 + row) * DD + kcol, (char*)Ksm + j * 4096 + w * 1024);
      }
    } else {  // stage V transposed: threads 256..511, 2 rows x 8 cols each
      const int u = t - 256;
      const int c8 = u & 7, r2 = u >> 3;
      const bf16* vs = &Vp[(size_t)(kv0 + r2 * 2) * DD + c8 * 8];
      u16x8 v0 = __builtin_bit_cast(u16x8, *(const bf16x8*)vs);
      u16x8 v1 = __builtin_bit_cast(u16x8, *(const bf16x8*)(vs + DD));
#pragma unroll
      for (int c = 0; c < 8; ++c) {
        const int d = c8 * 8 + c;
        const int off = d * 144 + ((r2 * 4) ^ (((d >> 3) & 7) << 4));
        *(unsigned*)((char*)Vtsm + off) = (unsigned)v0[c] | ((unsigned)v1[c] << 16);
      }
    }
    __syncthreads();
    if (kt <= lastkt) {
      // S = Q K^T / 8 : 16x64 per wave
      f32x4 s[4];
#pragma unroll
      for (int n = 0; n < 4; ++n) {
        f32x4 c = (f32x4)0.0f;
#pragma unroll
        for (int kc = 0; kc < 2; ++kc) {
          const int r = n * 16 + lr;
          bf16x8 kf = *(const bf16x8*)((const char*)Ksm + r * 128 +
                                       ((kc * 64 + lg * 16) ^ ((r & 7) << 4)));
          c = __builtin_amdgcn_mfma_f32_16x16x32_bf16(qf[kc], kf, c, 0, 0, 0);
        }
        s[n] = c * 0.125f;
      }
      if (kt == lastkt) {  // causal mask on this wave's diagonal tile
#pragma unroll
        for (int n = 0; n < 4; ++n) {
          const int kv = kv0 + n * 16 + lr;
#pragma unroll
          for (int r = 0; r < 4; ++r) {
            const int qq = q0 + w * 16 + lg * 4 + r;
            if (kv > qq) s[n][r] = -1e30f;
          }
        }
      }
      float alpha[4];
#pragma unroll
      for (int r = 0; r < 4; ++r) {
        float tm = fmaxf(fmaxf(s[0][r], s[1][r]), fmaxf(s[2][r], s[3][r]));
        tm = fmaxf(tm, __shfl_xor(tm, 1));
        tm = fmaxf(tm, __shfl_xor(tm, 2));
        tm = fmaxf(tm, __shfl_xor(tm, 4));
        tm = fmaxf(tm, __shfl_xor(tm, 8));
        const float mnew = fmaxf(mrun[r], tm);
        alpha[r] = __expf(mrun[r] - mnew);
        mrun[r] = mnew;
      }
#pragma unroll
      for (int r = 0; r < 4; ++r) {
        float acc = 0.0f;
#pragma unroll
        for (int n = 0; n < 4; ++n) {
          const float p = __expf(s[n][r] - mrun[r]);
          s[n][r] = p;
          acc += p;
        }
        acc += __shfl_xor(acc, 1);
        acc += __shfl_xor(acc, 2);
        acc += __shfl_xor(acc, 4);
        acc += __shfl_xor(acc, 8);
        lrun[r] = lrun[r] * alpha[r] + acc;
      }
#pragma unroll
      for (int dt = 0; dt < 4; ++dt)
#pragma unroll
        for (int r = 0; r < 4; ++r) o[dt][r] *= alpha[r];
      // P (C-layout) -> per-wave LDS -> A-fragments
#pragma unroll
      for (int n = 0; n < 4; ++n)
#pragma unroll
        for (int r = 0; r < 4; ++r) Psm[w][lg * 4 + r][n * 16 + lr] = (bf16)s[n][r];
      bf16x8 pf[2];
      pf[0] = *(const bf16x8*)&Psm[w][lr][lg * 8];
      pf[1] = *(const bf16x8*)&Psm[w][lr][32 + lg * 8];
#pragma unroll
      for (int dt = 0; dt < 4; ++dt)
#pragma unroll
        for (int kc = 0; kc < 2; ++kc) {
          const int dp = dt * 16 + lr;
          bf16x8 vf = *(const bf16x8*)((const char*)Vtsm + dp * 144 +
                                       ((kc * 64 + lg * 16) ^ (((dp >> 3) & 7) << 4)));
          o[dt] = __builtin_amdgcn_mfma_f32_16x16x32_bf16(pf[kc], vf, o[dt], 0, 0, 0);
        }
    }
    __syncthreads();
  }
#pragma unroll
  for (int dt = 0; dt < 4; ++dt) {
    const int d = dt * 16 + lr;
#pragma unroll
    for (int r = 0; r < 4; ++r) {
      const int qq = q0 + w * 16 + lg * 4 + r;
      ao[((size_t)b * SS + qq) * EE + h * DD + d] = (bf16)(o[dt][r] / lrun[r]);
    }
  }
}

extern "C" void kernel_launch(void* const* d_in, const int* in_sizes, int n_in,
                              void* d_out, int out_size, void* d_ws, size_t ws_size,
                              hipStream_t stream) {
  const float* v = (const float*)d_in[0];
  const float* k = (const float*)d_in[1];
  const float* q = (const float*)d_in[2];
  const float* wq = (const float*)d_in[4];
  const float* bq = (const float*)d_in[5];
  const float* wk = (const float*)d_in[6];
  const float* bk = (const float*)d_in[7];
  const float* wv = (const float*)d_in[8];
  const float* bv = (const float*)d_in[9];
  const float* wo = (const float*)d_in[10];
  const float* bo = (const float*)d_in[11];

  const size_t NTOK = (size_t)BB * SS * EE;  // 4,194,304
  bf16* wtb = (bf16*)d_ws;                   // [4][E][E]           8 MiB
  bf16* qb = wtb + (size_t)4 * EE * EE;      // [B*S][E] bf16       8 MiB
  bf16* qkvh = qb + NTOK;                    // [3][B][H][S][D]    24 MiB
  bf16* ao = qb;                             // reuse qb after QKV gemm
  bf16* kb = (bf16*)d_out;                   // scratch in d_out (overwritten at end)
  bf16* vb = kb + NTOK;

  cvt_k<<<dim3(512, 3), 256, 0, stream>>>(q, k, v, qb, kb, vb);
  wt_kernel<<<dim3(EE / 32, EE / 32, 4), dim3(32, 8), 0, stream>>>(wq, wk, wv, wo, wtb);
  gemm2<128, true><<<dim3(EE / 128, (BB * SS) / 128, 3), 256, 0, stream>>>(
      qb, kb, vb, wtb, bq, bk, bv, qkvh);
  attn_k<<<dim3(SS / 128, HH, BB), 512, 0, stream>>>(qkvh, ao);
  gemm2<64, false><<<dim3(EE / 64, (BB * SS) / 128, 1), 256, 0, stream>>>(
      ao, ao, ao, wtb + (size_t)3 * EE * EE, bo, bo, bo, d_out);
}

// Round 4
// 270.014 us; speedup vs baseline: 1.3486x; 1.0965x over previous
//
#include <hip/hip_runtime.h>
#include <hip/hip_bf16.h>

// MHA forward: B=2, S=2048, E=1024, H=16, D=64, causal.
// prep_k (cvt q/k/v -> bf16 + W -> W^T bf16) ;
// gemm2<128,true> QKV proj (global_load_lds + XOR swizzle; Q pre-scaled 1/8) ;
// attn_k (flash, swapped-QK 32x32 MFMA, in-register softmax, dbuf K/V) ;
// gemm2<64,false> out proj.

#define BB 2
#define SS 2048
#define EE 1024
#define HH 16
#define DD 64

typedef __bf16 bf16;
typedef __attribute__((ext_vector_type(8))) __bf16 bf16x8;
typedef __attribute__((ext_vector_type(8))) unsigned short u16x8;
typedef __attribute__((ext_vector_type(4))) float f32x4;
typedef __attribute__((ext_vector_type(16))) float f32x16;
typedef __attribute__((ext_vector_type(4))) unsigned u32x4;

__device__ __forceinline__ void gload16(const void* g, void* l) {
  __builtin_amdgcn_global_load_lds(
      (const __attribute__((address_space(1))) unsigned*)g,
      (__attribute__((address_space(3))) unsigned*)l, 16, 0, 0);
}

__device__ __forceinline__ unsigned pkbf(float x, float y) {
  unsigned a = (unsigned)__builtin_bit_cast(unsigned short, (bf16)x);
  unsigned b = (unsigned)__builtin_bit_cast(unsigned short, (bf16)y);
  return a | (b << 16);
}

// ---------------- prep: q/k/v f32->bf16  +  W -> W^T bf16 ----------------
__global__ __launch_bounds__(256) void prep_k(
    const float* __restrict__ q, const float* __restrict__ k, const float* __restrict__ v,
    bf16* __restrict__ qb, bf16* __restrict__ kb, bf16* __restrict__ vb,
    const float* __restrict__ w0, const float* __restrict__ w1,
    const float* __restrict__ w2, const float* __restrict__ w3, bf16* __restrict__ wt) {
  __shared__ float tile[32][33];
  const int bx = blockIdx.x, t = threadIdx.x;
  if (bx < 1536) {  // cvt: 512 blocks per z
    const int z = bx >> 9, blk = bx & 511;
    const float* s = z == 0 ? q : z == 1 ? k : v;
    bf16* d = z == 0 ? qb : z == 1 ? kb : vb;
    const size_t N8 = (size_t)BB * SS * EE / 8;
    for (size_t i = (size_t)blk * 256 + t; i < N8; i += (size_t)512 * 256) {
      f32x4 a = *(const f32x4*)(s + i * 8);
      f32x4 b = *(const f32x4*)(s + i * 8 + 4);
      bf16x8 o;
#pragma unroll
      for (int j = 0; j < 4; ++j) {
        o[j] = (bf16)a[j];
        o[j + 4] = (bf16)b[j];
      }
      *(bf16x8*)(d + i * 8) = o;
    }
  } else {  // wt: 1024 blocks per z
    const int u = bx - 1536;
    const int z = u >> 10, rem = u & 1023;
    const float* W = z == 0 ? w0 : z == 1 ? w1 : z == 2 ? w2 : w3;
    bf16* o = wt + (size_t)z * EE * EE;
    const int n0 = (rem & 31) * 32, k0 = (rem >> 5) * 32;
    const int tx = t & 31, ty = t >> 5;
#pragma unroll
    for (int j = 0; j < 4; ++j)
      tile[ty + j * 8][tx] = W[(size_t)(k0 + ty + j * 8) * EE + n0 + tx];
    __syncthreads();
#pragma unroll
    for (int j = 0; j < 4; ++j)
      o[(size_t)(n0 + ty + j * 8) * EE + k0 + tx] = (bf16)tile[tx][ty + j * 8];
  }
}

// ---------------- GEMM: C[M][N] = A[M][K] @ Wt[N][K]^T + bias ----------------
template <int BN, bool OUT_HEADS>
__global__ __launch_bounds__(256) void gemm2(
    const bf16* __restrict__ a0, const bf16* __restrict__ a1, const bf16* __restrict__ a2,
    const bf16* __restrict__ wtb, const float* __restrict__ bias0,
    const float* __restrict__ bias1, const float* __restrict__ bias2,
    void* __restrict__ outb) {
  constexpr int Kd = EE;
  constexpr int NJ = BN / 32;
  __shared__ __align__(16) bf16 Asm[128 * 64];
  __shared__ __align__(16) bf16 Bsm[BN * 64];
  const int t = threadIdx.x, lane = t & 63, w = t >> 6;
  const int lr = lane & 15, lg = lane >> 4;
  const int wm = w >> 1, wn = w & 1;
  const int m0 = blockIdx.y * 128, n0 = blockIdx.x * BN;
  const int z = blockIdx.z;
  const bf16* a = z == 0 ? a0 : z == 1 ? a1 : a2;
  const bf16* wt = wtb + (size_t)z * EE * EE;
  const float* bias = z == 0 ? bias0 : z == 1 ? bias1 : bias2;
  const float oscale = (OUT_HEADS && z == 0) ? 0.125f : 1.0f;  // fold 1/sqrt(D) into Q

  const int srow = lane >> 3;
  const int acol = ((lane & 7) ^ srow) * 8;

  f32x4 acc[4][NJ];
#pragma unroll
  for (int i = 0; i < 4; ++i)
#pragma unroll
    for (int j = 0; j < NJ; ++j) acc[i][j] = (f32x4)0.0f;

  for (int kk = 0; kk < Kd; kk += 64) {
#pragma unroll
    for (int j = 0; j < 4; ++j) {
      const int row = j * 32 + w * 8 + srow;
      gload16(a + (size_t)(m0 + row) * Kd + kk + acol, (char*)Asm + j * 4096 + w * 1024);
    }
#pragma unroll
    for (int j = 0; j < NJ; ++j) {
      const int row = j * 32 + w * 8 + srow;
      gload16(wt + (size_t)(n0 + row) * Kd + kk + acol, (char*)Bsm + j * 4096 + w * 1024);
    }
    __syncthreads();
#pragma unroll
    for (int kc = 0; kc < 2; ++kc) {
      bf16x8 A4[4], B4[NJ];
#pragma unroll
      for (int i = 0; i < 4; ++i) {
        const int r = wm * 64 + i * 16 + lr;
        A4[i] = *(const bf16x8*)((const char*)Asm + r * 128 + ((kc * 64 + lg * 16) ^ ((r & 7) << 4)));
      }
#pragma unroll
      for (int j = 0; j < NJ; ++j) {
        const int r = wn * (BN / 2) + j * 16 + lr;
        B4[j] = *(const bf16x8*)((const char*)Bsm + r * 128 + ((kc * 64 + lg * 16) ^ ((r & 7) << 4)));
      }
#pragma unroll
      for (int i = 0; i < 4; ++i)
#pragma unroll
        for (int j = 0; j < NJ; ++j)
          acc[i][j] = __builtin_amdgcn_mfma_f32_16x16x32_bf16(A4[i], B4[j], acc[i][j], 0, 0, 0);
    }
    __syncthreads();
  }
#pragma unroll
  for (int i = 0; i < 4; ++i)
#pragma unroll
    for (int j = 0; j < NJ; ++j) {
      const int col = n0 + wn * (BN / 2) + j * 16 + lr;
      const float bv = bias[col];
      const int row0 = m0 + wm * 64 + i * 16 + lg * 4;
#pragma unroll
      for (int r = 0; r < 4; ++r) {
        const int row = row0 + r;
        const float val = (acc[i][j][r] + bv) * oscale;
        if constexpr (OUT_HEADS) {
          bf16* o = (bf16*)outb + (size_t)z * BB * SS * EE;
          const int hh = col >> 6, dd = col & 63, bb = row >> 11, ss = row & 2047;
          o[(((size_t)bb * HH + hh) * SS + ss) * DD + dd] = (bf16)val;
        } else {
          ((float*)outb)[(size_t)row * EE + col] = val;
        }
      }
    }
}

// ---------------- flash attention: swapped-QK 32x32, in-register softmax ----------------
// grid (S/128, H, B), 256 threads = 4 waves; wave w owns q rows [J*128+w*32, +32).
// S^T = mfma(K,Q): lane holds q=lane&31, kv over regs at crow(r,hi)=(r&3)+8*(r>>2)+4*hi.
// O^T = mfma(V^T,P^T): lane holds q=lane&31 (alpha/lrun lane-local), d over regs.
__global__ __launch_bounds__(256) void attn_k(const bf16* __restrict__ qkvh,
                                              bf16* __restrict__ ao) {
  __shared__ __align__(16) char Ksm[2][8192];   // [kv 64][d 64] bf16, XOR-swizzled (gload_lds)
  __shared__ __align__(16) char Vtsm[2][9216];  // [d 64][kv 64+pad] bf16, XOR-swizzled
  const int J = (int)gridDim.x - 1 - (int)blockIdx.x;  // long blocks first
  const int h = blockIdx.y, b = blockIdx.z;
  const size_t hb = ((size_t)b * HH + h) * SS * DD;
  const bf16* Q = qkvh + hb;
  const bf16* Kp = qkvh + (size_t)BB * HH * SS * DD + hb;
  const bf16* Vp = qkvh + 2 * (size_t)BB * HH * SS * DD + hb;
  const int t = threadIdx.x, lane = t & 63, w = t >> 6;
  const int lq = lane & 31, hi = lane >> 5;
  const int q0 = J * 128;
  const int qrow = q0 + w * 32 + lq;

  bf16x8 qf[4];  // Q[qrow][kc*16 + hi*8 .. +8]  (B-frag of S^T)
#pragma unroll
  for (int kc = 0; kc < 4; ++kc)
    qf[kc] = *(const bf16x8*)&Q[(size_t)qrow * DD + kc * 16 + hi * 8];

  f32x16 o0 = (f32x16)0.f, o1 = (f32x16)0.f;  // O^T[d=crow+32*dt][q=lq]
  float mrun = -INFINITY, lrun = 0.f;

  const int srow = lane >> 3;
  const int kcol = ((lane & 7) ^ srow) * 8;  // pre-swizzled K source granule
  const int vr2 = t >> 3, vc8 = t & 7;       // V staging: rows vr2*2..+1, cols vc8*8..+7
  bf16x8 vreg0, vreg1;

  const int ktmax = 2 * J + 1;
  const int lastkt = 2 * J + (w >> 1);

  auto stage_load = [&](int kt) {
    const int kv0 = kt * 64;
    char* kdst = Ksm[kt & 1];
#pragma unroll
    for (int j = 0; j < 2; ++j)
      gload16(Kp + (size_t)(kv0 + j * 32 + w * 8 + srow) * DD + kcol, kdst + j * 4096 + w * 1024);
    const bf16* vs = Vp + (size_t)(kv0 + vr2 * 2) * DD + vc8 * 8;
    vreg0 = *(const bf16x8*)vs;
    vreg1 = *(const bf16x8*)(vs + DD);
  };
  auto stage_write = [&](int kt) {
    char* vdst = Vtsm[kt & 1];
    u16x8 a = __builtin_bit_cast(u16x8, vreg0), c = __builtin_bit_cast(u16x8, vreg1);
#pragma unroll
    for (int cc = 0; cc < 8; ++cc) {
      const int d = vc8 * 8 + cc;
      *(unsigned*)(vdst + d * 144 + ((vr2 * 4) ^ (((d >> 3) & 7) << 4))) =
          (unsigned)a[cc] | ((unsigned)c[cc] << 16);
    }
  };

  stage_load(0);
  stage_write(0);
  __syncthreads();

  for (int kt = 0; kt <= ktmax; ++kt) {
    const int cur = kt & 1;
    if (kt < ktmax) stage_load(kt + 1);
    if (kt <= lastkt) {
      const char* Kb = Ksm[cur];
      f32x16 sa = (f32x16)0.f, sb = (f32x16)0.f;  // S^T kv-blocks 0-31 / 32-63
      __builtin_amdgcn_s_setprio(1);
#pragma unroll
      for (int kc = 0; kc < 4; ++kc) {
        const int xo = (kc * 32 + hi * 16) ^ ((lq & 7) << 4);
        bf16x8 kf0 = *(const bf16x8*)(Kb + lq * 128 + xo);
        sa = __builtin_amdgcn_mfma_f32_32x32x16_bf16(kf0, qf[kc], sa, 0, 0, 0);
        bf16x8 kf1 = *(const bf16x8*)(Kb + (32 + lq) * 128 + xo);
        sb = __builtin_amdgcn_mfma_f32_32x32x16_bf16(kf1, qf[kc], sb, 0, 0, 0);
      }
      __builtin_amdgcn_s_setprio(0);
      if (kt == lastkt) {  // causal mask, lane-local
        const int kvb = kt * 64;
#pragma unroll
        for (int r = 0; r < 16; ++r) {
          const int kvo = kvb + (r & 3) + 8 * (r >> 2) + 4 * hi;
          if (kvo > qrow) sa[r] = -3.0e38f;
          if (kvo + 32 > qrow) sb[r] = -3.0e38f;
        }
      }
      // row max: in-register tree + one cross-half shfl
      float mx[8];
#pragma unroll
      for (int r = 0; r < 8; ++r)
        mx[r] = fmaxf(fmaxf(sa[r], sa[r + 8]), fmaxf(sb[r], sb[r + 8]));
#pragma unroll
      for (int st2 = 4; st2 > 0; st2 >>= 1)
#pragma unroll
        for (int r = 0; r < st2; ++r) mx[r] = fmaxf(mx[r], mx[r + st2]);
      const float tm = fmaxf(mx[0], __shfl_xor(mx[0], 32));
      const float mnew = fmaxf(mrun, tm);
      const float alpha = __expf(mrun - mnew);
      mrun = mnew;
#pragma unroll
      for (int r = 0; r < 16; ++r) {
        sa[r] = __expf(sa[r] - mnew);
        sb[r] = __expf(sb[r] - mnew);
      }
      float sum8[8];
#pragma unroll
      for (int r = 0; r < 8; ++r) sum8[r] = (sa[r] + sa[r + 8]) + (sb[r] + sb[r + 8]);
#pragma unroll
      for (int st2 = 4; st2 > 0; st2 >>= 1)
#pragma unroll
        for (int r = 0; r < st2; ++r) sum8[r] += sum8[r + st2];
      const float ts = sum8[0] + __shfl_xor(sum8[0], 32);
      lrun = lrun * alpha + ts;
      o0 *= alpha;
      o1 *= alpha;
      // pack P -> bf16 words; exchange halves (partner holds kv offsets +-4)
      unsigned pA0[4], pB0[4], pA1[4], pB1[4];
#pragma unroll
      for (int g = 0; g < 4; ++g) {
        pA0[g] = pkbf(sa[4 * g], sa[4 * g + 1]);
        pB0[g] = pkbf(sa[4 * g + 2], sa[4 * g + 3]);
        pA1[g] = pkbf(sb[4 * g], sb[4 * g + 1]);
        pB1[g] = pkbf(sb[4 * g + 2], sb[4 * g + 3]);
      }
      unsigned qA0[4], qB0[4], qA1[4], qB1[4];
#pragma unroll
      for (int g = 0; g < 4; ++g) {
        qA0[g] = __shfl_xor(pA0[g], 32);
        qB0[g] = __shfl_xor(pB0[g], 32);
        qA1[g] = __shfl_xor(pA1[g], 32);
        qB1[g] = __shfl_xor(pB1[g], 32);
      }
      const char* Vb = Vtsm[cur];
      __builtin_amdgcn_s_setprio(1);
#pragma unroll
      for (int ks = 0; ks < 4; ++ks) {  // P^T B-frag: kv = ks*16 + hi*8 + e
        const int gA = 2 * (ks & 1), gB = gA + 1;
        unsigned w0, w1, w2, w3;
        if (ks < 2) {
          w0 = hi ? qA0[gB] : pA0[gA];
          w1 = hi ? qB0[gB] : pB0[gA];
          w2 = hi ? pA0[gB] : qA0[gA];
          w3 = hi ? pB0[gB] : qB0[gA];
        } else {
          w0 = hi ? qA1[gB] : pA1[gA];
          w1 = hi ? qB1[gB] : pB1[gA];
          w2 = hi ? pA1[gB] : qA1[gA];
          w3 = hi ? pB1[gB] : qB1[gA];
        }
        u32x4 wv = {w0, w1, w2, w3};
        bf16x8 pf = __builtin_bit_cast(bf16x8, wv);
        const int xo = ks * 32 + hi * 16;
        bf16x8 vf0 = *(const bf16x8*)(Vb + lq * 144 + (xo ^ (((lq >> 3) & 7) << 4)));
        o0 = __builtin_amdgcn_mfma_f32_32x32x16_bf16(vf0, pf, o0, 0, 0, 0);
        const int dp1 = 32 + lq;
        bf16x8 vf1 = *(const bf16x8*)(Vb + dp1 * 144 + (xo ^ (((dp1 >> 3) & 7) << 4)));
        o1 = __builtin_amdgcn_mfma_f32_32x32x16_bf16(vf1, pf, o1, 0, 0, 0);
      }
      __builtin_amdgcn_s_setprio(0);
    }
    if (kt < ktmax) stage_write(kt + 1);
    __syncthreads();
  }
  // epilogue: O^T[d][q] -> ao[b][q][h*64+d], lane-local 1/lrun
  const float invl = 1.0f / lrun;
  bf16* orow = ao + ((size_t)b * SS + qrow) * EE + h * DD;
#pragma unroll
  for (int r = 0; r < 16; r += 2) {
    const int d0 = (r >> 2) * 8 + 4 * hi + (r & 3);
    *(unsigned*)(orow + d0) = pkbf(o0[r] * invl, o0[r + 1] * invl);
    *(unsigned*)(orow + 32 + d0) = pkbf(o1[r] * invl, o1[r + 1] * invl);
  }
}

extern "C" void kernel_launch(void* const* d_in, const int* in_sizes, int n_in,
                              void* d_out, int out_size, void* d_ws, size_t ws_size,
                              hipStream_t stream) {
  const float* v = (const float*)d_in[0];
  const float* k = (const float*)d_in[1];
  const float* q = (const float*)d_in[2];
  const float* wq = (const float*)d_in[4];
  const float* bq = (const float*)d_in[5];
  const float* wk = (const float*)d_in[6];
  const float* bk = (const float*)d_in[7];
  const float* wv = (const float*)d_in[8];
  const float* bv = (const float*)d_in[9];
  const float* wo = (const float*)d_in[10];
  const float* bo = (const float*)d_in[11];

  const size_t NTOK = (size_t)BB * SS * EE;
  bf16* wtb = (bf16*)d_ws;                 // [4][E][E]          8 MiB
  bf16* qb = wtb + (size_t)4 * EE * EE;    // [B*S][E]           8 MiB
  bf16* qkvh = qb + NTOK;                  // [3][B][H][S][D]   24 MiB
  bf16* ao = qb;                           // reuse qb after QKV gemm
  bf16* kb = (bf16*)d_out;                 // scratch in d_out
  bf16* vb = kb + NTOK;

  prep_k<<<dim3(1536 + 4096), 256, 0, stream>>>(q, k, v, qb, kb, vb, wq, wk, wv, wo, wtb);
  gemm2<128, true><<<dim3(EE / 128, (BB * SS) / 128, 3), 256, 0, stream>>>(
      qb, kb, vb, wtb, bq, bk, bv, qkvh);
  attn_k<<<dim3(SS / 128, HH, BB), 256, 0, stream>>>(qkvh, ao);
  gemm2<64, false><<<dim3(EE / 64, (BB * SS) / 128, 1), 256, 0, stream>>>(
      ao, ao, ao, wtb + (size_t)3 * EE * EE, bo, bo, bo, d_out);
}

// Round 7
// 266.813 us; speedup vs baseline: 1.3648x; 1.0120x over previous
//
#include <hip/hip_runtime.h>
#include <hip/hip_bf16.h>

// MHA forward: B=2, S=2048, E=1024, H=16, D=64, causal.
// prep_k (cvt q/k/v -> bf16 + W -> W^T bf16) ;
// gemm2<128,true> QKV proj (global_load_lds + XOR swizzle; Q pre-scaled by log2e/8) ;
// attn_k (flash, swapped-QK 32x32 MFMA, in-register exp2 softmax, dbuf K/V,
//         qtile=64, 2-wave blocks, 1024 blocks -> 4 blocks/CU) ;
// gemm2<64,false> out proj.

#define BB 2
#define SS 2048
#define EE 1024
#define HH 16
#define DD 64

typedef __bf16 bf16;
typedef __attribute__((ext_vector_type(8))) __bf16 bf16x8;
typedef __attribute__((ext_vector_type(8))) unsigned short u16x8;
typedef __attribute__((ext_vector_type(4))) float f32x4;
typedef __attribute__((ext_vector_type(16))) float f32x16;
typedef __attribute__((ext_vector_type(4))) unsigned u32x4;

#define EXP2(x) __builtin_amdgcn_exp2f(x)

__device__ __forceinline__ void gload16(const void* g, void* l) {
  __builtin_amdgcn_global_load_lds(
      (const __attribute__((address_space(1))) unsigned*)g,
      (__attribute__((address_space(3))) unsigned*)l, 16, 0, 0);
}

__device__ __forceinline__ unsigned pkbf(float x, float y) {
  unsigned a = (unsigned)__builtin_bit_cast(unsigned short, (bf16)x);
  unsigned b = (unsigned)__builtin_bit_cast(unsigned short, (bf16)y);
  return a | (b << 16);
}

// ---------------- prep: q/k/v f32->bf16  +  W -> W^T bf16 ----------------
__global__ __launch_bounds__(256) void prep_k(
    const float* __restrict__ q, const float* __restrict__ k, const float* __restrict__ v,
    bf16* __restrict__ qb, bf16* __restrict__ kb, bf16* __restrict__ vb,
    const float* __restrict__ w0, const float* __restrict__ w1,
    const float* __restrict__ w2, const float* __restrict__ w3, bf16* __restrict__ wt) {
  __shared__ float tile[32][33];
  const int bx = blockIdx.x, t = threadIdx.x;
  if (bx < 1536) {  // cvt: 512 blocks per z
    const int z = bx >> 9, blk = bx & 511;
    const float* s = z == 0 ? q : z == 1 ? k : v;
    bf16* d = z == 0 ? qb : z == 1 ? kb : vb;
    const size_t N8 = (size_t)BB * SS * EE / 8;
    for (size_t i = (size_t)blk * 256 + t; i < N8; i += (size_t)512 * 256) {
      f32x4 a = *(const f32x4*)(s + i * 8);
      f32x4 b = *(const f32x4*)(s + i * 8 + 4);
      bf16x8 o;
#pragma unroll
      for (int j = 0; j < 4; ++j) {
        o[j] = (bf16)a[j];
        o[j + 4] = (bf16)b[j];
      }
      *(bf16x8*)(d + i * 8) = o;
    }
  } else {  // wt: 1024 blocks per z
    const int u = bx - 1536;
    const int z = u >> 10, rem = u & 1023;
    const float* W = z == 0 ? w0 : z == 1 ? w1 : z == 2 ? w2 : w3;
    bf16* o = wt + (size_t)z * EE * EE;
    const int n0 = (rem & 31) * 32, k0 = (rem >> 5) * 32;
    const int tx = t & 31, ty = t >> 5;
#pragma unroll
    for (int j = 0; j < 4; ++j)
      tile[ty + j * 8][tx] = W[(size_t)(k0 + ty + j * 8) * EE + n0 + tx];
    __syncthreads();
#pragma unroll
    for (int j = 0; j < 4; ++j)
      o[(size_t)(n0 + ty + j * 8) * EE + k0 + tx] = (bf16)tile[tx][ty + j * 8];
  }
}

// ---------------- GEMM: C[M][N] = A[M][K] @ Wt[N][K]^T + bias ----------------
template <int BN, bool OUT_HEADS>
__global__ __launch_bounds__(256) void gemm2(
    const bf16* __restrict__ a0, const bf16* __restrict__ a1, const bf16* __restrict__ a2,
    const bf16* __restrict__ wtb, const float* __restrict__ bias0,
    const float* __restrict__ bias1, const float* __restrict__ bias2,
    void* __restrict__ outb) {
  constexpr int Kd = EE;
  constexpr int NJ = BN / 32;
  __shared__ __align__(16) bf16 Asm[128 * 64];
  __shared__ __align__(16) bf16 Bsm[BN * 64];
  const int t = threadIdx.x, lane = t & 63, w = t >> 6;
  const int lr = lane & 15, lg = lane >> 4;
  const int wm = w >> 1, wn = w & 1;
  const int m0 = blockIdx.y * 128, n0 = blockIdx.x * BN;
  const int z = blockIdx.z;
  const bf16* a = z == 0 ? a0 : z == 1 ? a1 : a2;
  const bf16* wt = wtb + (size_t)z * EE * EE;
  const float* bias = z == 0 ? bias0 : z == 1 ? bias1 : bias2;
  // fold 1/sqrt(D) * log2(e) into Q so attention softmax runs in exp2 space
  const float oscale = (OUT_HEADS && z == 0) ? 0.125f * 1.44269504f : 1.0f;

  const int srow = lane >> 3;
  const int acol = ((lane & 7) ^ srow) * 8;

  f32x4 acc[4][NJ];
#pragma unroll
  for (int i = 0; i < 4; ++i)
#pragma unroll
    for (int j = 0; j < NJ; ++j) acc[i][j] = (f32x4)0.0f;

  for (int kk = 0; kk < Kd; kk += 64) {
#pragma unroll
    for (int j = 0; j < 4; ++j) {
      const int row = j * 32 + w * 8 + srow;
      gload16(a + (size_t)(m0 + row) * Kd + kk + acol, (char*)Asm + j * 4096 + w * 1024);
    }
#pragma unroll
    for (int j = 0; j < NJ; ++j) {
      const int row = j * 32 + w * 8 + srow;
      gload16(wt + (size_t)(n0 + row) * Kd + kk + acol, (char*)Bsm + j * 4096 + w * 1024);
    }
    __syncthreads();
#pragma unroll
    for (int kc = 0; kc < 2; ++kc) {
      bf16x8 A4[4], B4[NJ];
#pragma unroll
      for (int i = 0; i < 4; ++i) {
        const int r = wm * 64 + i * 16 + lr;
        A4[i] = *(const bf16x8*)((const char*)Asm + r * 128 + ((kc * 64 + lg * 16) ^ ((r & 7) << 4)));
      }
#pragma unroll
      for (int j = 0; j < NJ; ++j) {
        const int r = wn * (BN / 2) + j * 16 + lr;
        B4[j] = *(const bf16x8*)((const char*)Bsm + r * 128 + ((kc * 64 + lg * 16) ^ ((r & 7) << 4)));
      }
#pragma unroll
      for (int i = 0; i < 4; ++i)
#pragma unroll
        for (int j = 0; j < NJ; ++j)
          acc[i][j] = __builtin_amdgcn_mfma_f32_16x16x32_bf16(A4[i], B4[j], acc[i][j], 0, 0, 0);
    }
    __syncthreads();
  }
#pragma unroll
  for (int i = 0; i < 4; ++i)
#pragma unroll
    for (int j = 0; j < NJ; ++j) {
      const int col = n0 + wn * (BN / 2) + j * 16 + lr;
      const float bv = bias[col];
      const int row0 = m0 + wm * 64 + i * 16 + lg * 4;
#pragma unroll
      for (int r = 0; r < 4; ++r) {
        const int row = row0 + r;
        const float val = (acc[i][j][r] + bv) * oscale;
        if constexpr (OUT_HEADS) {
          bf16* o = (bf16*)outb + (size_t)z * BB * SS * EE;
          const int hh = col >> 6, dd = col & 63, bb = row >> 11, ss = row & 2047;
          o[(((size_t)bb * HH + hh) * SS + ss) * DD + dd] = (bf16)val;
        } else {
          ((float*)outb)[(size_t)row * EE + col] = val;
        }
      }
    }
}

// ---------------- flash attention: swapped-QK 32x32, in-register exp2 softmax ----------
// grid (S/64, H, B) reversed; 128 threads = 2 waves; wave w owns q rows [J*64+w*32,+32).
// S^T = mfma(K,Q): lane holds q=lane&31, kv over regs at crow(r,hi)=(r&3)+8*(r>>2)+4*hi.
// O^T = mfma(V^T,P^T): lane holds q=lane&31 (alpha/lrun lane-local), d over regs.
__global__ __launch_bounds__(128) void attn_k(const bf16* __restrict__ qkvh,
                                              bf16* __restrict__ ao) {
  __shared__ __align__(16) char Ksm[2][8192];   // [kv 64][d 64] bf16, XOR-swizzled (gload_lds)
  __shared__ __align__(16) char Vtsm[2][9216];  // [d 64][kv 64] bf16, stride 144, XOR-swizzled
  const int J = (int)gridDim.x - 1 - (int)blockIdx.x;  // long blocks first
  const int h = blockIdx.y, b = blockIdx.z;
  const size_t hb = ((size_t)b * HH + h) * SS * DD;
  const bf16* Q = qkvh + hb;
  const bf16* Kp = qkvh + (size_t)BB * HH * SS * DD + hb;
  const bf16* Vp = qkvh + 2 * (size_t)BB * HH * SS * DD + hb;
  const int t = threadIdx.x, lane = t & 63, w = t >> 6;
  const int lq = lane & 31, hi = lane >> 5;
  const int q0 = J * 64;
  const int qrow = q0 + w * 32 + lq;

  bf16x8 qf[4];  // Q[qrow][kc*16 + hi*8 .. +8]  (B-frag of S^T)
#pragma unroll
  for (int kc = 0; kc < 4; ++kc)
    qf[kc] = *(const bf16x8*)&Q[(size_t)qrow * DD + kc * 16 + hi * 8];

  f32x16 o0 = (f32x16)0.f, o1 = (f32x16)0.f;  // O^T[d=crow+32*dt][q=lq]
  float mrun = -INFINITY, lrun = 0.f;

  const int srow = lane >> 3;
  const int kcol = ((lane & 7) ^ srow) * 8;  // pre-swizzled K source granule
  const int vr2 = t >> 3, vc8 = t & 7;       // V staging: 16 row-pairs x 8 col-groups
  bf16x8 vreg[4];

  const int ktmax = J;  // kv tiles 0..J

  auto stage_load = [&](int kt) {
    const int kv0 = kt * 64;
    char* kdst = Ksm[kt & 1];
#pragma unroll
    for (int j = 0; j < 4; ++j)
      gload16(Kp + (size_t)(kv0 + j * 16 + w * 8 + srow) * DD + kcol, kdst + j * 2048 + w * 1024);
#pragma unroll
    for (int p = 0; p < 2; ++p) {
      const bf16* vs = Vp + (size_t)(kv0 + p * 32 + vr2 * 2) * DD + vc8 * 8;
      vreg[2 * p] = *(const bf16x8*)vs;
      vreg[2 * p + 1] = *(const bf16x8*)(vs + DD);
    }
  };
  auto stage_write = [&](int kt) {
    char* vdst = Vtsm[kt & 1];
#pragma unroll
    for (int p = 0; p < 2; ++p) {
      u16x8 a = __builtin_bit_cast(u16x8, vreg[2 * p]);
      u16x8 c = __builtin_bit_cast(u16x8, vreg[2 * p + 1]);
      const int r2 = p * 16 + vr2;
#pragma unroll
      for (int cc = 0; cc < 8; ++cc) {
        const int d = vc8 * 8 + cc;
        *(unsigned*)(vdst + d * 144 + ((r2 * 4) ^ (((d >> 3) & 7) << 4))) =
            (unsigned)a[cc] | ((unsigned)c[cc] << 16);
      }
    }
  };

  stage_load(0);
  stage_write(0);
  __syncthreads();

  for (int kt = 0; kt <= ktmax; ++kt) {
    const int cur = kt & 1;
    if (kt < ktmax) stage_load(kt + 1);
    {
      const char* Kb = Ksm[cur];
      f32x16 sa = (f32x16)0.f, sb = (f32x16)0.f;  // S^T kv-blocks 0-31 / 32-63
      __builtin_amdgcn_s_setprio(1);
#pragma unroll
      for (int kc = 0; kc < 4; ++kc) {
        const int xo = (kc * 32 + hi * 16) ^ ((lq & 7) << 4);
        bf16x8 kf0 = *(const bf16x8*)(Kb + lq * 128 + xo);
        sa = __builtin_amdgcn_mfma_f32_32x32x16_bf16(kf0, qf[kc], sa, 0, 0, 0);
        bf16x8 kf1 = *(const bf16x8*)(Kb + (32 + lq) * 128 + xo);
        sb = __builtin_amdgcn_mfma_f32_32x32x16_bf16(kf1, qf[kc], sb, 0, 0, 0);
      }
      __builtin_amdgcn_s_setprio(0);
      if (kt == ktmax) {  // causal mask, lane-local
        const int kvb = kt * 64;
#pragma unroll
        for (int r = 0; r < 16; ++r) {
          const int kvo = kvb + (r & 3) + 8 * (r >> 2) + 4 * hi;
          if (kvo > qrow) sa[r] = -3.0e38f;
          if (kvo + 32 > qrow) sb[r] = -3.0e38f;
        }
      }
      // row max: in-register tree + one cross-half shfl (all in log2 space)
      float mx[8];
#pragma unroll
      for (int r = 0; r < 8; ++r)
        mx[r] = fmaxf(fmaxf(sa[r], sa[r + 8]), fmaxf(sb[r], sb[r + 8]));
#pragma unroll
      for (int st2 = 4; st2 > 0; st2 >>= 1)
#pragma unroll
        for (int r = 0; r < st2; ++r) mx[r] = fmaxf(mx[r], mx[r + st2]);
      const float tm = fmaxf(mx[0], __shfl_xor(mx[0], 32));
      const float mnew = fmaxf(mrun, tm);
      const float alpha = EXP2(mrun - mnew);
      mrun = mnew;
#pragma unroll
      for (int r = 0; r < 16; ++r) {
        sa[r] = EXP2(sa[r] - mnew);
        sb[r] = EXP2(sb[r] - mnew);
      }
      float sum8[8];
#pragma unroll
      for (int r = 0; r < 8; ++r) sum8[r] = (sa[r] + sa[r + 8]) + (sb[r] + sb[r + 8]);
#pragma unroll
      for (int st2 = 4; st2 > 0; st2 >>= 1)
#pragma unroll
        for (int r = 0; r < st2; ++r) sum8[r] += sum8[r + st2];
      const float ts = sum8[0] + __shfl_xor(sum8[0], 32);
      lrun = lrun * alpha + ts;
      o0 *= alpha;
      o1 *= alpha;
      // pack P -> bf16 words; exchange halves (partner holds kv offsets +-4)
      unsigned pA0[4], pB0[4], pA1[4], pB1[4];
#pragma unroll
      for (int g = 0; g < 4; ++g) {
        pA0[g] = pkbf(sa[4 * g], sa[4 * g + 1]);
        pB0[g] = pkbf(sa[4 * g + 2], sa[4 * g + 3]);
        pA1[g] = pkbf(sb[4 * g], sb[4 * g + 1]);
        pB1[g] = pkbf(sb[4 * g + 2], sb[4 * g + 3]);
      }
      unsigned qA0[4], qB0[4], qA1[4], qB1[4];
#pragma unroll
      for (int g = 0; g < 4; ++g) {
        qA0[g] = __shfl_xor(pA0[g], 32);
        qB0[g] = __shfl_xor(pB0[g], 32);
        qA1[g] = __shfl_xor(pA1[g], 32);
        qB1[g] = __shfl_xor(pB1[g], 32);
      }
      const char* Vb = Vtsm[cur];
      __builtin_amdgcn_s_setprio(1);
#pragma unroll
      for (int ks = 0; ks < 4; ++ks) {  // P^T B-frag: kv = ks*16 + hi*8 + e
        const int gA = 2 * (ks & 1), gB = gA + 1;
        unsigned w0, w1, w2, w3;
        if (ks < 2) {
          w0 = hi ? qA0[gB] : pA0[gA];
          w1 = hi ? qB0[gB] : pB0[gA];
          w2 = hi ? pA0[gB] : qA0[gA];
          w3 = hi ? pB0[gB] : qB0[gA];
        } else {
          w0 = hi ? qA1[gB] : pA1[gA];
          w1 = hi ? qB1[gB] : pB1[gA];
          w2 = hi ? pA1[gB] : qA1[gA];
          w3 = hi ? pB1[gB] : qB1[gA];
        }
        u32x4 wv = {w0, w1, w2, w3};
        bf16x8 pf = __builtin_bit_cast(bf16x8, wv);
        const int xo = ks * 32 + hi * 16;
        bf16x8 vf0 = *(const bf16x8*)(Vb + lq * 144 + (xo ^ (((lq >> 3) & 7) << 4)));
        o0 = __builtin_amdgcn_mfma_f32_32x32x16_bf16(vf0, pf, o0, 0, 0, 0);
        const int dp1 = 32 + lq;
        bf16x8 vf1 = *(const bf16x8*)(Vb + dp1 * 144 + (xo ^ (((dp1 >> 3) & 7) << 4)));
        o1 = __builtin_amdgcn_mfma_f32_32x32x16_bf16(vf1, pf, o1, 0, 0, 0);
      }
      __builtin_amdgcn_s_setprio(0);
    }
    if (kt < ktmax) stage_write(kt + 1);
    __syncthreads();
  }
  // epilogue: O^T[d][q] -> ao[b][q][h*64+d], lane-local 1/lrun
  const float invl = 1.0f / lrun;
  bf16* orow = ao + ((size_t)b * SS + qrow) * EE + h * DD;
#pragma unroll
  for (int r = 0; r < 16; r += 2) {
    const int d0 = (r >> 2) * 8 + 4 * hi + (r & 3);
    *(unsigned*)(orow + d0) = pkbf(o0[r] * invl, o0[r + 1] * invl);
    *(unsigned*)(orow + 32 + d0) = pkbf(o1[r] * invl, o1[r + 1] * invl);
  }
}

extern "C" void kernel_launch(void* const* d_in, const int* in_sizes, int n_in,
                              void* d_out, int out_size, void* d_ws, size_t ws_size,
                              hipStream_t stream) {
  const float* v = (const float*)d_in[0];
  const float* k = (const float*)d_in[1];
  const float* q = (const float*)d_in[2];
  const float* wq = (const float*)d_in[4];
  const float* bq = (const float*)d_in[5];
  const float* wk = (const float*)d_in[6];
  const float* bk = (const float*)d_in[7];
  const float* wv = (const float*)d_in[8];
  const float* bv = (const float*)d_in[9];
  const float* wo = (const float*)d_in[10];
  const float* bo = (const float*)d_in[11];

  const size_t NTOK = (size_t)BB * SS * EE;
  bf16* wtb = (bf16*)d_ws;               // [4][E][E]          8 MiB
  bf16* qb = wtb + (size_t)4 * EE * EE;  // [B*S][E]           8 MiB
  bf16* qkvh = qb + NTOK;                // [3][B][H][S][D]   24 MiB
  bf16* ao = qb;                         // reuse qb after QKV gemm
  bf16* kb = (bf16*)d_out;               // scratch in d_out
  bf16* vb = kb + NTOK;

  prep_k<<<dim3(1536 + 4096), 256, 0, stream>>>(q, k, v, qb, kb, vb, wq, wk, wv, wo, wtb);
  gemm2<128, true><<<dim3(EE / 128, (BB * SS) / 128, 3), 256, 0, stream>>>(
      qb, kb, vb, wtb, bq, bk, bv, qkvh);
  attn_k<<<dim3(SS / 64, HH, BB), 128, 0, stream>>>(qkvh, ao);
  gemm2<64, false><<<dim3(EE / 64, (BB * SS) / 128, 1), 256, 0, stream>>>(
      ao, ao, ao, wtb + (size_t)3 * EE * EE, bo, bo, bo, d_out);
}

// Round 8
// 260.100 us; speedup vs baseline: 1.4000x; 1.0258x over previous
//
#include <hip/hip_runtime.h>
#include <hip/hip_bf16.h>

// MHA forward: B=2, S=2048, E=1024, H=16, D=64, causal.
// prep_k (cvt q/k/v -> bf16 + W -> W^T bf16) ;
// gemm2<128,true> QKV proj (global_load_lds + XOR swizzle; Q pre-scaled by log2e/8) ;
// attn_k (flash, swapped-QK 32x32 MFMA, in-register exp2 softmax, dbuf K/V,
//         CAUSAL FOLD: block = q-tiles {P, 31-P}, 4 waves, constant 33-tile work) ;
// gemm2<64,false> out proj.

#define BB 2
#define SS 2048
#define EE 1024
#define HH 16
#define DD 64

typedef __bf16 bf16;
typedef __attribute__((ext_vector_type(8))) __bf16 bf16x8;
typedef __attribute__((ext_vector_type(8))) unsigned short u16x8;
typedef __attribute__((ext_vector_type(4))) float f32x4;
typedef __attribute__((ext_vector_type(16))) float f32x16;
typedef __attribute__((ext_vector_type(4))) unsigned u32x4;

#define EXP2(x) __builtin_amdgcn_exp2f(x)

__device__ __forceinline__ void gload16(const void* g, void* l) {
  __builtin_amdgcn_global_load_lds(
      (const __attribute__((address_space(1))) unsigned*)g,
      (__attribute__((address_space(3))) unsigned*)l, 16, 0, 0);
}

__device__ __forceinline__ unsigned pkbf(float x, float y) {
  unsigned a = (unsigned)__builtin_bit_cast(unsigned short, (bf16)x);
  unsigned b = (unsigned)__builtin_bit_cast(unsigned short, (bf16)y);
  return a | (b << 16);
}

// ---------------- prep: q/k/v f32->bf16  +  W -> W^T bf16 ----------------
__global__ __launch_bounds__(256) void prep_k(
    const float* __restrict__ q, const float* __restrict__ k, const float* __restrict__ v,
    bf16* __restrict__ qb, bf16* __restrict__ kb, bf16* __restrict__ vb,
    const float* __restrict__ w0, const float* __restrict__ w1,
    const float* __restrict__ w2, const float* __restrict__ w3, bf16* __restrict__ wt) {
  __shared__ float tile[32][33];
  const int bx = blockIdx.x, t = threadIdx.x;
  if (bx < 1536) {  // cvt: 512 blocks per z
    const int z = bx >> 9, blk = bx & 511;
    const float* s = z == 0 ? q : z == 1 ? k : v;
    bf16* d = z == 0 ? qb : z == 1 ? kb : vb;
    const size_t N8 = (size_t)BB * SS * EE / 8;
    for (size_t i = (size_t)blk * 256 + t; i < N8; i += (size_t)512 * 256) {
      f32x4 a = *(const f32x4*)(s + i * 8);
      f32x4 b = *(const f32x4*)(s + i * 8 + 4);
      bf16x8 o;
#pragma unroll
      for (int j = 0; j < 4; ++j) {
        o[j] = (bf16)a[j];
        o[j + 4] = (bf16)b[j];
      }
      *(bf16x8*)(d + i * 8) = o;
    }
  } else {  // wt: 1024 blocks per z
    const int u = bx - 1536;
    const int z = u >> 10, rem = u & 1023;
    const float* W = z == 0 ? w0 : z == 1 ? w1 : z == 2 ? w2 : w3;
    bf16* o = wt + (size_t)z * EE * EE;
    const int n0 = (rem & 31) * 32, k0 = (rem >> 5) * 32;
    const int tx = t & 31, ty = t >> 5;
#pragma unroll
    for (int j = 0; j < 4; ++j)
      tile[ty + j * 8][tx] = W[(size_t)(k0 + ty + j * 8) * EE + n0 + tx];
    __syncthreads();
#pragma unroll
    for (int j = 0; j < 4; ++j)
      o[(size_t)(n0 + ty + j * 8) * EE + k0 + tx] = (bf16)tile[tx][ty + j * 8];
  }
}

// ---------------- GEMM: C[M][N] = A[M][K] @ Wt[N][K]^T + bias ----------------
template <int BN, bool OUT_HEADS>
__global__ __launch_bounds__(256) void gemm2(
    const bf16* __restrict__ a0, const bf16* __restrict__ a1, const bf16* __restrict__ a2,
    const bf16* __restrict__ wtb, const float* __restrict__ bias0,
    const float* __restrict__ bias1, const float* __restrict__ bias2,
    void* __restrict__ outb) {
  constexpr int Kd = EE;
  constexpr int NJ = BN / 32;
  __shared__ __align__(16) bf16 Asm[128 * 64];
  __shared__ __align__(16) bf16 Bsm[BN * 64];
  const int t = threadIdx.x, lane = t & 63, w = t >> 6;
  const int lr = lane & 15, lg = lane >> 4;
  const int wm = w >> 1, wn = w & 1;
  const int m0 = blockIdx.y * 128, n0 = blockIdx.x * BN;
  const int z = blockIdx.z;
  const bf16* a = z == 0 ? a0 : z == 1 ? a1 : a2;
  const bf16* wt = wtb + (size_t)z * EE * EE;
  const float* bias = z == 0 ? bias0 : z == 1 ? bias1 : bias2;
  // fold 1/sqrt(D) * log2(e) into Q so attention softmax runs in exp2 space
  const float oscale = (OUT_HEADS && z == 0) ? 0.125f * 1.44269504f : 1.0f;

  const int srow = lane >> 3;
  const int acol = ((lane & 7) ^ srow) * 8;

  f32x4 acc[4][NJ];
#pragma unroll
  for (int i = 0; i < 4; ++i)
#pragma unroll
    for (int j = 0; j < NJ; ++j) acc[i][j] = (f32x4)0.0f;

  for (int kk = 0; kk < Kd; kk += 64) {
#pragma unroll
    for (int j = 0; j < 4; ++j) {
      const int row = j * 32 + w * 8 + srow;
      gload16(a + (size_t)(m0 + row) * Kd + kk + acol, (char*)Asm + j * 4096 + w * 1024);
    }
#pragma unroll
    for (int j = 0; j < NJ; ++j) {
      const int row = j * 32 + w * 8 + srow;
      gload16(wt + (size_t)(n0 + row) * Kd + kk + acol, (char*)Bsm + j * 4096 + w * 1024);
    }
    __syncthreads();
#pragma unroll
    for (int kc = 0; kc < 2; ++kc) {
      bf16x8 A4[4], B4[NJ];
#pragma unroll
      for (int i = 0; i < 4; ++i) {
        const int r = wm * 64 + i * 16 + lr;
        A4[i] = *(const bf16x8*)((const char*)Asm + r * 128 + ((kc * 64 + lg * 16) ^ ((r & 7) << 4)));
      }
#pragma unroll
      for (int j = 0; j < NJ; ++j) {
        const int r = wn * (BN / 2) + j * 16 + lr;
        B4[j] = *(const bf16x8*)((const char*)Bsm + r * 128 + ((kc * 64 + lg * 16) ^ ((r & 7) << 4)));
      }
#pragma unroll
      for (int i = 0; i < 4; ++i)
#pragma unroll
        for (int j = 0; j < NJ; ++j)
          acc[i][j] = __builtin_amdgcn_mfma_f32_16x16x32_bf16(A4[i], B4[j], acc[i][j], 0, 0, 0);
    }
    __syncthreads();
  }
#pragma unroll
  for (int i = 0; i < 4; ++i)
#pragma unroll
    for (int j = 0; j < NJ; ++j) {
      const int col = n0 + wn * (BN / 2) + j * 16 + lr;
      const float bv = bias[col];
      const int row0 = m0 + wm * 64 + i * 16 + lg * 4;
#pragma unroll
      for (int r = 0; r < 4; ++r) {
        const int row = row0 + r;
        const float val = (acc[i][j][r] + bv) * oscale;
        if constexpr (OUT_HEADS) {
          bf16* o = (bf16*)outb + (size_t)z * BB * SS * EE;
          const int hh = col >> 6, dd = col & 63, bb = row >> 11, ss = row & 2047;
          o[(((size_t)bb * HH + hh) * SS + ss) * DD + dd] = (bf16)val;
        } else {
          ((float*)outb)[(size_t)row * EE + col] = val;
        }
      }
    }
}

// ---------------- flash attention: causal fold, swapped-QK 32x32, exp2 softmax --------
// grid (16, H, B), 256 threads = 4 waves. Waves 0-1 own q-tile J1=P (rows J1*64..+63),
// waves 2-3 own q-tile J2=31-P. One shared K/V staging loop kt=0..J2; wave computes
// while kt <= its J (mask at kt==J). Every block does (J1+1)+(J2+1)=33 compute-tiles.
// S^T = mfma(K,Q): lane holds q=lane&31, kv at crow(r,hi)=(r&3)+8*(r>>2)+4*hi.
// O^T = mfma(V^T,P^T): lane holds q=lane&31 (alpha/lrun lane-local), d over regs.
__global__ __launch_bounds__(256) void attn_k(const bf16* __restrict__ qkvh,
                                              bf16* __restrict__ ao) {
  __shared__ __align__(16) char Ksm[2][8192];   // [kv 64][d 64] bf16, XOR-swizzled (gload_lds)
  __shared__ __align__(16) char Vtsm[2][9216];  // [d 64][kv 64] bf16, stride 144, XOR-swizzled
  const int P = blockIdx.x;  // pair index 0..15
  const int h = blockIdx.y, b = blockIdx.z;
  const size_t hb = ((size_t)b * HH + h) * SS * DD;
  const bf16* Q = qkvh + hb;
  const bf16* Kp = qkvh + (size_t)BB * HH * SS * DD + hb;
  const bf16* Vp = qkvh + 2 * (size_t)BB * HH * SS * DD + hb;
  const int t = threadIdx.x, lane = t & 63, w = t >> 6;
  const int lq = lane & 31, hi = lane >> 5;
  const int J = (w >> 1) == 0 ? P : 31 - P;  // this wave's q-tile
  const int qrow = J * 64 + (w & 1) * 32 + lq;
  const int lastkt = J;        // mask tile for this wave
  const int ktmax = 31 - P;    // shared staging range (J2 >= J1 always)

  bf16x8 qf[4];  // Q[qrow][kc*16 + hi*8 .. +8]  (B-frag of S^T)
#pragma unroll
  for (int kc = 0; kc < 4; ++kc)
    qf[kc] = *(const bf16x8*)&Q[(size_t)qrow * DD + kc * 16 + hi * 8];

  f32x16 o0 = (f32x16)0.f, o1 = (f32x16)0.f;  // O^T[d=crow+32*dt][q=lq]
  float mrun = -INFINITY, lrun = 0.f;

  const int srow = lane >> 3;
  const int kcol = ((lane & 7) ^ srow) * 8;  // pre-swizzled K source granule
  const int vr2 = t >> 3, vc8 = t & 7;       // V staging: 32 row-pairs x 8 col-groups
  bf16x8 vreg0, vreg1;

  auto stage_load = [&](int kt) {
    const int kv0 = kt * 64;
    char* kdst = Ksm[kt & 1];
#pragma unroll
    for (int j = 0; j < 2; ++j)
      gload16(Kp + (size_t)(kv0 + j * 32 + w * 8 + srow) * DD + kcol, kdst + j * 4096 + w * 1024);
    const bf16* vs = Vp + (size_t)(kv0 + vr2 * 2) * DD + vc8 * 8;
    vreg0 = *(const bf16x8*)vs;
    vreg1 = *(const bf16x8*)(vs + DD);
  };
  auto stage_write = [&](int kt) {
    char* vdst = Vtsm[kt & 1];
    u16x8 a = __builtin_bit_cast(u16x8, vreg0);
    u16x8 c = __builtin_bit_cast(u16x8, vreg1);
#pragma unroll
    for (int cc = 0; cc < 8; ++cc) {
      const int d = vc8 * 8 + cc;
      *(unsigned*)(vdst + d * 144 + ((vr2 * 4) ^ (((d >> 3) & 7) << 4))) =
          (unsigned)a[cc] | ((unsigned)c[cc] << 16);
    }
  };

  stage_load(0);
  stage_write(0);
  __syncthreads();

  for (int kt = 0; kt <= ktmax; ++kt) {
    const int cur = kt & 1;
    if (kt < ktmax) stage_load(kt + 1);
    if (kt <= lastkt) {
      const char* Kb = Ksm[cur];
      f32x16 sa = (f32x16)0.f, sb = (f32x16)0.f;  // S^T kv-blocks 0-31 / 32-63
      __builtin_amdgcn_s_setprio(1);
#pragma unroll
      for (int kc = 0; kc < 4; ++kc) {
        const int xo = (kc * 32 + hi * 16) ^ ((lq & 7) << 4);
        bf16x8 kf0 = *(const bf16x8*)(Kb + lq * 128 + xo);
        sa = __builtin_amdgcn_mfma_f32_32x32x16_bf16(kf0, qf[kc], sa, 0, 0, 0);
        bf16x8 kf1 = *(const bf16x8*)(Kb + (32 + lq) * 128 + xo);
        sb = __builtin_amdgcn_mfma_f32_32x32x16_bf16(kf1, qf[kc], sb, 0, 0, 0);
      }
      __builtin_amdgcn_s_setprio(0);
      if (kt == lastkt) {  // causal mask, lane-local
        const int kvb = kt * 64;
#pragma unroll
        for (int r = 0; r < 16; ++r) {
          const int kvo = kvb + (r & 3) + 8 * (r >> 2) + 4 * hi;
          if (kvo > qrow) sa[r] = -3.0e38f;
          if (kvo + 32 > qrow) sb[r] = -3.0e38f;
        }
      }
      // row max: in-register tree + one cross-half shfl (all in log2 space)
      float mx[8];
#pragma unroll
      for (int r = 0; r < 8; ++r)
        mx[r] = fmaxf(fmaxf(sa[r], sa[r + 8]), fmaxf(sb[r], sb[r + 8]));
#pragma unroll
      for (int st2 = 4; st2 > 0; st2 >>= 1)
#pragma unroll
        for (int r = 0; r < st2; ++r) mx[r] = fmaxf(mx[r], mx[r + st2]);
      const float tm = fmaxf(mx[0], __shfl_xor(mx[0], 32));
      // defer-max (T13): only rescale when the running max grows by >8 (log2 units)
      if (__any(tm > mrun + 8.0f)) {
        const float mnew = fmaxf(mrun, tm);
        const float alpha = EXP2(mrun - mnew);
        lrun *= alpha;
        o0 *= alpha;
        o1 *= alpha;
        mrun = mnew;
      }
#pragma unroll
      for (int r = 0; r < 16; ++r) {
        sa[r] = EXP2(sa[r] - mrun);
        sb[r] = EXP2(sb[r] - mrun);
      }
      float sum8[8];
#pragma unroll
      for (int r = 0; r < 8; ++r) sum8[r] = (sa[r] + sa[r + 8]) + (sb[r] + sb[r + 8]);
#pragma unroll
      for (int st2 = 4; st2 > 0; st2 >>= 1)
#pragma unroll
        for (int r = 0; r < st2; ++r) sum8[r] += sum8[r + st2];
      lrun += sum8[0] + __shfl_xor(sum8[0], 32);
      // pack P -> bf16 words; exchange halves (partner holds kv offsets +-4)
      unsigned pA0[4], pB0[4], pA1[4], pB1[4];
#pragma unroll
      for (int g = 0; g < 4; ++g) {
        pA0[g] = pkbf(sa[4 * g], sa[4 * g + 1]);
        pB0[g] = pkbf(sa[4 * g + 2], sa[4 * g + 3]);
        pA1[g] = pkbf(sb[4 * g], sb[4 * g + 1]);
        pB1[g] = pkbf(sb[4 * g + 2], sb[4 * g + 3]);
      }
      unsigned qA0[4], qB0[4], qA1[4], qB1[4];
#pragma unroll
      for (int g = 0; g < 4; ++g) {
        qA0[g] = __shfl_xor(pA0[g], 32);
        qB0[g] = __shfl_xor(pB0[g], 32);
        qA1[g] = __shfl_xor(pA1[g], 32);
        qB1[g] = __shfl_xor(pB1[g], 32);
      }
      const char* Vb = Vtsm[cur];
      __builtin_amdgcn_s_setprio(1);
#pragma unroll
      for (int ks = 0; ks < 4; ++ks) {  // P^T B-frag: kv = ks*16 + hi*8 + e
        const int gA = 2 * (ks & 1), gB = gA + 1;
        unsigned w0, w1, w2, w3;
        if (ks < 2) {
          w0 = hi ? qA0[gB] : pA0[gA];
          w1 = hi ? qB0[gB] : pB0[gA];
          w2 = hi ? pA0[gB] : qA0[gA];
          w3 = hi ? pB0[gB] : qB0[gA];
        } else {
          w0 = hi ? qA1[gB] : pA1[gA];
          w1 = hi ? qB1[gB] : pB1[gA];
          w2 = hi ? pA1[gB] : qA1[gA];
          w3 = hi ? pB1[gB] : qB1[gA];
        }
        u32x4 wv = {w0, w1, w2, w3};
        bf16x8 pf = __builtin_bit_cast(bf16x8, wv);
        const int xo = ks * 32 + hi * 16;
        bf16x8 vf0 = *(const bf16x8*)(Vb + lq * 144 + (xo ^ (((lq >> 3) & 7) << 4)));
        o0 = __builtin_amdgcn_mfma_f32_32x32x16_bf16(vf0, pf, o0, 0, 0, 0);
        const int dp1 = 32 + lq;
        bf16x8 vf1 = *(const bf16x8*)(Vb + dp1 * 144 + (xo ^ (((dp1 >> 3) & 7) << 4)));
        o1 = __builtin_amdgcn_mfma_f32_32x32x16_bf16(vf1, pf, o1, 0, 0, 0);
      }
      __builtin_amdgcn_s_setprio(0);
    }
    if (kt < ktmax) stage_write(kt + 1);
    __syncthreads();
  }
  // epilogue: O^T[d][q] -> ao[b][q][h*64+d], lane-local 1/lrun
  const float invl = 1.0f / lrun;
  bf16* orow = ao + ((size_t)b * SS + qrow) * EE + h * DD;
#pragma unroll
  for (int r = 0; r < 16; r += 2) {
    const int d0 = (r >> 2) * 8 + 4 * hi + (r & 3);
    *(unsigned*)(orow + d0) = pkbf(o0[r] * invl, o0[r + 1] * invl);
    *(unsigned*)(orow + 32 + d0) = pkbf(o1[r] * invl, o1[r + 1] * invl);
  }
}

extern "C" void kernel_launch(void* const* d_in, const int* in_sizes, int n_in,
                              void* d_out, int out_size, void* d_ws, size_t ws_size,
                              hipStream_t stream) {
  const float* v = (const float*)d_in[0];
  const float* k = (const float*)d_in[1];
  const float* q = (const float*)d_in[2];
  const float* wq = (const float*)d_in[4];
  const float* bq = (const float*)d_in[5];
  const float* wk = (const float*)d_in[6];
  const float* bk = (const float*)d_in[7];
  const float* wv = (const float*)d_in[8];
  const float* bv = (const float*)d_in[9];
  const float* wo = (const float*)d_in[10];
  const float* bo = (const float*)d_in[11];

  const size_t NTOK = (size_t)BB * SS * EE;
  bf16* wtb = (bf16*)d_ws;               // [4][E][E]          8 MiB
  bf16* qb = wtb + (size_t)4 * EE * EE;  // [B*S][E]           8 MiB
  bf16* qkvh = qb + NTOK;                // [3][B][H][S][D]   24 MiB
  bf16* ao = qb;                         // reuse qb after QKV gemm
  bf16* kb = (bf16*)d_out;               // scratch in d_out
  bf16* vb = kb + NTOK;

  prep_k<<<dim3(1536 + 4096), 256, 0, stream>>>(q, k, v, qb, kb, vb, wq, wk, wv, wo, wtb);
  gemm2<128, true><<<dim3(EE / 128, (BB * SS) / 128, 3), 256, 0, stream>>>(
      qb, kb, vb, wtb, bq, bk, bv, qkvh);
  attn_k<<<dim3(SS / 128, HH, BB), 256, 0, stream>>>(qkvh, ao);
  gemm2<64, false><<<dim3(EE / 64, (BB * SS) / 128, 1), 256, 0, stream>>>(
      ao, ao, ao, wtb + (size_t)3 * EE * EE, bo, bo, bo, d_out);
}

// Round 9
// 254.091 us; speedup vs baseline: 1.4332x; 1.0236x over previous
//
#include <hip/hip_runtime.h>
#include <hip/hip_bf16.h>

// MHA forward: B=2, S=2048, E=1024, H=16, D=64, causal.
// prep_k (cvt q/k/v -> bf16 + W -> W^T bf16) ;
// gemm2<128,true> QKV proj (global_load_lds + XOR swizzle; C^T mfma -> vector stores) ;
// attn_k (flash, swapped-QK 32x32 MFMA, exp2 softmax, dbuf K/V, causal fold,
//         XCD-aware (P,h,b) swizzle: per-XCD KV residency + per-CU 49-tile balance) ;
// gemm2<64,false> out proj.

#define BB 2
#define SS 2048
#define EE 1024
#define HH 16
#define DD 64

typedef __bf16 bf16;
typedef __attribute__((ext_vector_type(8))) __bf16 bf16x8;
typedef __attribute__((ext_vector_type(8))) unsigned short u16x8;
typedef __attribute__((ext_vector_type(4))) float f32x4;
typedef __attribute__((ext_vector_type(16))) float f32x16;
typedef __attribute__((ext_vector_type(4))) unsigned u32x4;
typedef __attribute__((ext_vector_type(2))) unsigned u32x2;

#define EXP2(x) __builtin_amdgcn_exp2f(x)

__device__ __forceinline__ void gload16(const void* g, void* l) {
  __builtin_amdgcn_global_load_lds(
      (const __attribute__((address_space(1))) unsigned*)g,
      (__attribute__((address_space(3))) unsigned*)l, 16, 0, 0);
}

__device__ __forceinline__ unsigned pkbf(float x, float y) {
  unsigned a = (unsigned)__builtin_bit_cast(unsigned short, (bf16)x);
  unsigned b = (unsigned)__builtin_bit_cast(unsigned short, (bf16)y);
  return a | (b << 16);
}

// ---------------- prep: q/k/v f32->bf16  +  W -> W^T bf16 ----------------
__global__ __launch_bounds__(256) void prep_k(
    const float* __restrict__ q, const float* __restrict__ k, const float* __restrict__ v,
    bf16* __restrict__ qb, bf16* __restrict__ kb, bf16* __restrict__ vb,
    const float* __restrict__ w0, const float* __restrict__ w1,
    const float* __restrict__ w2, const float* __restrict__ w3, bf16* __restrict__ wt) {
  __shared__ float tile[32][33];
  const int bx = blockIdx.x, t = threadIdx.x;
  if (bx < 1536) {  // cvt: 512 blocks per z
    const int z = bx >> 9, blk = bx & 511;
    const float* s = z == 0 ? q : z == 1 ? k : v;
    bf16* d = z == 0 ? qb : z == 1 ? kb : vb;
    const size_t N8 = (size_t)BB * SS * EE / 8;
    for (size_t i = (size_t)blk * 256 + t; i < N8; i += (size_t)512 * 256) {
      f32x4 a = *(const f32x4*)(s + i * 8);
      f32x4 b = *(const f32x4*)(s + i * 8 + 4);
      bf16x8 o;
#pragma unroll
      for (int j = 0; j < 4; ++j) {
        o[j] = (bf16)a[j];
        o[j + 4] = (bf16)b[j];
      }
      *(bf16x8*)(d + i * 8) = o;
    }
  } else {  // wt: 1024 blocks per z
    const int u = bx - 1536;
    const int z = u >> 10, rem = u & 1023;
    const float* W = z == 0 ? w0 : z == 1 ? w1 : z == 2 ? w2 : w3;
    bf16* o = wt + (size_t)z * EE * EE;
    const int n0 = (rem & 31) * 32, k0 = (rem >> 5) * 32;
    const int tx = t & 31, ty = t >> 5;
#pragma unroll
    for (int j = 0; j < 4; ++j)
      tile[ty + j * 8][tx] = W[(size_t)(k0 + ty + j * 8) * EE + n0 + tx];
    __syncthreads();
#pragma unroll
    for (int j = 0; j < 4; ++j)
      o[(size_t)(n0 + ty + j * 8) * EE + k0 + tx] = (bf16)tile[tx][ty + j * 8];
  }
}

// ---------------- GEMM: C[M][N] = A[M][K] @ Wt[N][K]^T + bias ----------------
// MFMA computes C^T (operands swapped): per lane, acc[i][j] holds 4 CONSECUTIVE
// columns (n = nb..nb+3) of one row m -> vectorized epilogue stores.
template <int BN, bool OUT_HEADS>
__global__ __launch_bounds__(256) void gemm2(
    const bf16* __restrict__ a0, const bf16* __restrict__ a1, const bf16* __restrict__ a2,
    const bf16* __restrict__ wtb, const float* __restrict__ bias0,
    const float* __restrict__ bias1, const float* __restrict__ bias2,
    void* __restrict__ outb) {
  constexpr int Kd = EE;
  constexpr int NJ = BN / 32;
  __shared__ __align__(16) bf16 Asm[128 * 64];
  __shared__ __align__(16) bf16 Bsm[BN * 64];
  const int t = threadIdx.x, lane = t & 63, w = t >> 6;
  const int lr = lane & 15, lg = lane >> 4;
  const int wm = w >> 1, wn = w & 1;
  const int m0 = blockIdx.y * 128, n0 = blockIdx.x * BN;
  const int z = blockIdx.z;
  const bf16* a = z == 0 ? a0 : z == 1 ? a1 : a2;
  const bf16* wt = wtb + (size_t)z * EE * EE;
  const float* bias = z == 0 ? bias0 : z == 1 ? bias1 : bias2;
  // fold 1/sqrt(D) * log2(e) into Q so attention softmax runs in exp2 space
  const float oscale = (OUT_HEADS && z == 0) ? 0.125f * 1.44269504f : 1.0f;

  const int srow = lane >> 3;
  const int acol = ((lane & 7) ^ srow) * 8;

  f32x4 acc[4][NJ];
#pragma unroll
  for (int i = 0; i < 4; ++i)
#pragma unroll
    for (int j = 0; j < NJ; ++j) acc[i][j] = (f32x4)0.0f;

  for (int kk = 0; kk < Kd; kk += 64) {
#pragma unroll
    for (int j = 0; j < 4; ++j) {
      const int row = j * 32 + w * 8 + srow;
      gload16(a + (size_t)(m0 + row) * Kd + kk + acol, (char*)Asm + j * 4096 + w * 1024);
    }
#pragma unroll
    for (int j = 0; j < NJ; ++j) {
      const int row = j * 32 + w * 8 + srow;
      gload16(wt + (size_t)(n0 + row) * Kd + kk + acol, (char*)Bsm + j * 4096 + w * 1024);
    }
    __syncthreads();
#pragma unroll
    for (int kc = 0; kc < 2; ++kc) {
      bf16x8 A4[4], B4[NJ];
#pragma unroll
      for (int i = 0; i < 4; ++i) {
        const int r = wm * 64 + i * 16 + lr;
        A4[i] = *(const bf16x8*)((const char*)Asm + r * 128 + ((kc * 64 + lg * 16) ^ ((r & 7) << 4)));
      }
#pragma unroll
      for (int j = 0; j < NJ; ++j) {
        const int r = wn * (BN / 2) + j * 16 + lr;
        B4[j] = *(const bf16x8*)((const char*)Bsm + r * 128 + ((kc * 64 + lg * 16) ^ ((r & 7) << 4)));
      }
#pragma unroll
      for (int i = 0; i < 4; ++i)
#pragma unroll
        for (int j = 0; j < NJ; ++j)  // swapped: D^T, rows=n, cols=m
          acc[i][j] = __builtin_amdgcn_mfma_f32_16x16x32_bf16(B4[j], A4[i], acc[i][j], 0, 0, 0);
    }
    __syncthreads();
  }
  // epilogue: lane holds row m = m0+wm*64+i*16+lr, cols nb..nb+3 (nb = ...+lg*4)
#pragma unroll
  for (int i = 0; i < 4; ++i)
#pragma unroll
    for (int j = 0; j < NJ; ++j) {
      const int m = m0 + wm * 64 + i * 16 + lr;
      const int nb = n0 + wn * (BN / 2) + j * 16 + lg * 4;
      const f32x4 bv = *(const f32x4*)&bias[nb];
      f32x4 val;
#pragma unroll
      for (int r = 0; r < 4; ++r) val[r] = (acc[i][j][r] + bv[r]) * oscale;
      if constexpr (OUT_HEADS) {
        bf16* o = (bf16*)outb + (size_t)z * BB * SS * EE;
        const int hh = nb >> 6, dd = nb & 63, bb = m >> 11, ss = m & 2047;
        u32x2 pk;
        pk[0] = pkbf(val[0], val[1]);
        pk[1] = pkbf(val[2], val[3]);
        *(u32x2*)&o[(((size_t)bb * HH + hh) * SS + ss) * DD + dd] = pk;
      } else {
        *(f32x4*)((float*)outb + (size_t)m * EE + nb) = val;
      }
    }
}

// ---------------- flash attention: causal fold, swapped-QK 32x32, exp2 softmax --------
// grid (16,16,2) = 512 blocks, 256 threads = 4 waves. Flat block id F remapped:
// xcd=F&7 owns h in {2*xcd, 2*xcd+1} (KV+Q ~3MB fits 4MB L2); per-CU slot pair
// (P, 15-P) -> constant 49 staged tiles per CU. Waves 0-1: q-tile J1=P, waves 2-3:
// J2=31-P; shared K/V staging loop kt=0..31-P.
// S^T = mfma(K,Q): lane holds q=lane&31, kv at crow(r,hi)=(r&3)+8*(r>>2)+4*hi.
// O^T = mfma(V^T,P^T): lane holds q=lane&31 (alpha/lrun lane-local), d over regs.
__global__ __launch_bounds__(256) void attn_k(const bf16* __restrict__ qkvh,
                                              bf16* __restrict__ ao) {
  __shared__ __align__(16) char Ksm[2][8192];   // [kv 64][d 64] bf16, XOR-swizzled (gload_lds)
  __shared__ __align__(16) char Vtsm[2][9216];  // [d 64][kv 64] bf16, stride 144, XOR-swizzled
  const int F = (int)blockIdx.x + 16 * ((int)blockIdx.y + 16 * (int)blockIdx.z);
  const int xcd = F & 7;
  const int rest = F >> 3;   // 0..63
  const int sb = rest >> 5;  // second CU slot -> b=1, complementary P
  const int tt = rest & 31;
  const int h = xcd * 2 + (tt & 1);
  const int P0 = tt >> 1;
  const int P = sb ? 15 - P0 : P0;
  const int b = sb;
  const size_t hb = ((size_t)b * HH + h) * SS * DD;
  const bf16* Q = qkvh + hb;
  const bf16* Kp = qkvh + (size_t)BB * HH * SS * DD + hb;
  const bf16* Vp = qkvh + 2 * (size_t)BB * HH * SS * DD + hb;
  const int t = threadIdx.x, lane = t & 63, w = t >> 6;
  const int lq = lane & 31, hi = lane >> 5;
  const int J = (w >> 1) == 0 ? P : 31 - P;  // this wave's q-tile
  const int qrow = J * 64 + (w & 1) * 32 + lq;
  const int lastkt = J;      // mask tile for this wave
  const int ktmax = 31 - P;  // shared staging range (J2 >= J1 always)

  bf16x8 qf[4];  // Q[qrow][kc*16 + hi*8 .. +8]  (B-frag of S^T)
#pragma unroll
  for (int kc = 0; kc < 4; ++kc)
    qf[kc] = *(const bf16x8*)&Q[(size_t)qrow * DD + kc * 16 + hi * 8];

  f32x16 o0 = (f32x16)0.f, o1 = (f32x16)0.f;  // O^T[d=crow+32*dt][q=lq]
  float mrun = -INFINITY, lrun = 0.f;

  const int srow = lane >> 3;
  const int kcol = ((lane & 7) ^ srow) * 8;  // pre-swizzled K source granule
  const int vr2 = t >> 3, vc8 = t & 7;       // V staging: 32 row-pairs x 8 col-groups
  bf16x8 vreg0, vreg1;

  auto stage_load = [&](int kt) {
    const int kv0 = kt * 64;
    char* kdst = Ksm[kt & 1];
#pragma unroll
    for (int j = 0; j < 2; ++j)
      gload16(Kp + (size_t)(kv0 + j * 32 + w * 8 + srow) * DD + kcol, kdst + j * 4096 + w * 1024);
    const bf16* vs = Vp + (size_t)(kv0 + vr2 * 2) * DD + vc8 * 8;
    vreg0 = *(const bf16x8*)vs;
    vreg1 = *(const bf16x8*)(vs + DD);
  };
  auto stage_write = [&](int kt) {
    char* vdst = Vtsm[kt & 1];
    u16x8 a = __builtin_bit_cast(u16x8, vreg0);
    u16x8 c = __builtin_bit_cast(u16x8, vreg1);
#pragma unroll
    for (int cc = 0; cc < 8; ++cc) {
      const int d = vc8 * 8 + cc;
      *(unsigned*)(vdst + d * 144 + ((vr2 * 4) ^ (((d >> 3) & 7) << 4))) =
          (unsigned)a[cc] | ((unsigned)c[cc] << 16);
    }
  };

  stage_load(0);
  stage_write(0);
  __syncthreads();

  for (int kt = 0; kt <= ktmax; ++kt) {
    const int cur = kt & 1;
    if (kt < ktmax) stage_load(kt + 1);
    if (kt <= lastkt) {
      const char* Kb = Ksm[cur];
      f32x16 sa = (f32x16)0.f, sb2 = (f32x16)0.f;  // S^T kv-blocks 0-31 / 32-63
      __builtin_amdgcn_s_setprio(1);
#pragma unroll
      for (int kc = 0; kc < 4; ++kc) {
        const int xo = (kc * 32 + hi * 16) ^ ((lq & 7) << 4);
        bf16x8 kf0 = *(const bf16x8*)(Kb + lq * 128 + xo);
        sa = __builtin_amdgcn_mfma_f32_32x32x16_bf16(kf0, qf[kc], sa, 0, 0, 0);
        bf16x8 kf1 = *(const bf16x8*)(Kb + (32 + lq) * 128 + xo);
        sb2 = __builtin_amdgcn_mfma_f32_32x32x16_bf16(kf1, qf[kc], sb2, 0, 0, 0);
      }
      __builtin_amdgcn_s_setprio(0);
      if (kt == lastkt) {  // causal mask, lane-local
        const int kvb = kt * 64;
#pragma unroll
        for (int r = 0; r < 16; ++r) {
          const int kvo = kvb + (r & 3) + 8 * (r >> 2) + 4 * hi;
          if (kvo > qrow) sa[r] = -3.0e38f;
          if (kvo + 32 > qrow) sb2[r] = -3.0e38f;
        }
      }
      // row max: in-register tree + one cross-half shfl (all in log2 space)
      float mx[8];
#pragma unroll
      for (int r = 0; r < 8; ++r)
        mx[r] = fmaxf(fmaxf(sa[r], sa[r + 8]), fmaxf(sb2[r], sb2[r + 8]));
#pragma unroll
      for (int st2 = 4; st2 > 0; st2 >>= 1)
#pragma unroll
        for (int r = 0; r < st2; ++r) mx[r] = fmaxf(mx[r], mx[r + st2]);
      const float tm = fmaxf(mx[0], __shfl_xor(mx[0], 32));
      // defer-max (T13): only rescale when the running max grows by >8 (log2 units)
      if (__any(tm > mrun + 8.0f)) {
        const float mnew = fmaxf(mrun, tm);
        const float alpha = EXP2(mrun - mnew);
        lrun *= alpha;
        o0 *= alpha;
        o1 *= alpha;
        mrun = mnew;
      }
#pragma unroll
      for (int r = 0; r < 16; ++r) {
        sa[r] = EXP2(sa[r] - mrun);
        sb2[r] = EXP2(sb2[r] - mrun);
      }
      float sum8[8];
#pragma unroll
      for (int r = 0; r < 8; ++r) sum8[r] = (sa[r] + sa[r + 8]) + (sb2[r] + sb2[r + 8]);
#pragma unroll
      for (int st2 = 4; st2 > 0; st2 >>= 1)
#pragma unroll
        for (int r = 0; r < st2; ++r) sum8[r] += sum8[r + st2];
      lrun += sum8[0] + __shfl_xor(sum8[0], 32);
      // pack P -> bf16 words; exchange halves (partner holds kv offsets +-4)
      unsigned pA0[4], pB0[4], pA1[4], pB1[4];
#pragma unroll
      for (int g = 0; g < 4; ++g) {
        pA0[g] = pkbf(sa[4 * g], sa[4 * g + 1]);
        pB0[g] = pkbf(sa[4 * g + 2], sa[4 * g + 3]);
        pA1[g] = pkbf(sb2[4 * g], sb2[4 * g + 1]);
        pB1[g] = pkbf(sb2[4 * g + 2], sb2[4 * g + 3]);
      }
      unsigned qA0[4], qB0[4], qA1[4], qB1[4];
#pragma unroll
      for (int g = 0; g < 4; ++g) {
        qA0[g] = __shfl_xor(pA0[g], 32);
        qB0[g] = __shfl_xor(pB0[g], 32);
        qA1[g] = __shfl_xor(pA1[g], 32);
        qB1[g] = __shfl_xor(pB1[g], 32);
      }
      const char* Vb = Vtsm[cur];
      __builtin_amdgcn_s_setprio(1);
#pragma unroll
      for (int ks = 0; ks < 4; ++ks) {  // P^T B-frag: kv = ks*16 + hi*8 + e
        const int gA = 2 * (ks & 1), gB = gA + 1;
        unsigned w0, w1, w2, w3;
        if (ks < 2) {
          w0 = hi ? qA0[gB] : pA0[gA];
          w1 = hi ? qB0[gB] : pB0[gA];
          w2 = hi ? pA0[gB] : qA0[gA];
          w3 = hi ? pB0[gB] : qB0[gA];
        } else {
          w0 = hi ? qA1[gB] : pA1[gA];
          w1 = hi ? qB1[gB] : pB1[gA];
          w2 = hi ? pA1[gB] : qA1[gA];
          w3 = hi ? pB1[gB] : qB1[gA];
        }
        u32x4 wv = {w0, w1, w2, w3};
        bf16x8 pf = __builtin_bit_cast(bf16x8, wv);
        const int xo = ks * 32 + hi * 16;
        bf16x8 vf0 = *(const bf16x8*)(Vb + lq * 144 + (xo ^ (((lq >> 3) & 7) << 4)));
        o0 = __builtin_amdgcn_mfma_f32_32x32x16_bf16(vf0, pf, o0, 0, 0, 0);
        const int dp1 = 32 + lq;
        bf16x8 vf1 = *(const bf16x8*)(Vb + dp1 * 144 + (xo ^ (((dp1 >> 3) & 7) << 4)));
        o1 = __builtin_amdgcn_mfma_f32_32x32x16_bf16(vf1, pf, o1, 0, 0, 0);
      }
      __builtin_amdgcn_s_setprio(0);
    }
    if (kt < ktmax) stage_write(kt + 1);
    __syncthreads();
  }
  // epilogue: O^T[d][q] -> ao[b][q][h*64+d], lane-local 1/lrun
  const float invl = 1.0f / lrun;
  bf16* orow = ao + ((size_t)b * SS + qrow) * EE + h * DD;
#pragma unroll
  for (int r = 0; r < 16; r += 2) {
    const int d0 = (r >> 2) * 8 + 4 * hi + (r & 3);
    *(unsigned*)(orow + d0) = pkbf(o0[r] * invl, o0[r + 1] * invl);
    *(unsigned*)(orow + 32 + d0) = pkbf(o1[r] * invl, o1[r + 1] * invl);
  }
}

extern "C" void kernel_launch(void* const* d_in, const int* in_sizes, int n_in,
                              void* d_out, int out_size, void* d_ws, size_t ws_size,
                              hipStream_t stream) {
  const float* v = (const float*)d_in[0];
  const float* k = (const float*)d_in[1];
  const float* q = (const float*)d_in[2];
  const float* wq = (const float*)d_in[4];
  const float* bq = (const float*)d_in[5];
  const float* wk = (const float*)d_in[6];
  const float* bk = (const float*)d_in[7];
  const float* wv = (const float*)d_in[8];
  const float* bv = (const float*)d_in[9];
  const float* wo = (const float*)d_in[10];
  const float* bo = (const float*)d_in[11];

  const size_t NTOK = (size_t)BB * SS * EE;
  bf16* wtb = (bf16*)d_ws;               // [4][E][E]          8 MiB
  bf16* qb = wtb + (size_t)4 * EE * EE;  // [B*S][E]           8 MiB
  bf16* qkvh = qb + NTOK;                // [3][B][H][S][D]   24 MiB
  bf16* ao = qb;                         // reuse qb after QKV gemm
  bf16* kb = (bf16*)d_out;               // scratch in d_out
  bf16* vb = kb + NTOK;

  prep_k<<<dim3(1536 + 4096), 256, 0, stream>>>(q, k, v, qb, kb, vb, wq, wk, wv, wo, wtb);
  gemm2<128, true><<<dim3(EE / 128, (BB * SS) / 128, 3), 256, 0, stream>>>(
      qb, kb, vb, wtb, bq, bk, bv, qkvh);
  attn_k<<<dim3(SS / 128, HH, BB), 256, 0, stream>>>(qkvh, ao);
  gemm2<64, false><<<dim3(EE / 64, (BB * SS) / 128, 1), 256, 0, stream>>>(
      ao, ao, ao, wtb + (size_t)3 * EE * EE, bo, bo, bo, d_out);
}